// Round 11
// baseline (692.264 us; speedup 1.0000x reference)
//
#include <hip/hip_runtime.h>
#include <math.h>

#define B_   8
#define C_   96
#define C2_  192
#define N_   3136        // 56*56
#define R_   25088       // B_*N_
#define OUP_ 192
#define HO_  28
#define NO_  784         // 28*28
#define EPS_ 1e-5f
#define QS2  128         // fspH point stride in u16 (256 B); ch 96/97 = split(-sq/2), 98-127 zero
#define CAP3 64          // per-row candidate pool cap

typedef short bf16x8 __attribute__((ext_vector_type(8)));
typedef float f32x4  __attribute__((ext_vector_type(4)));

// uint4-slot XOR swizzle within a 64-row x 16-slot tile (T2): col ^= row&7
__device__ __forceinline__ int swz16(int i) { return (i & ~15) | ((i & 15) ^ ((i >> 4) & 7)); }

// ---------------- fc1 (fp64 accumulate): yd[b,d,n] = sum_c x[b,c,n]*W1[c,d] + b1[d] ----------------
__global__ __launch_bounds__(512) void k_fc1_d(const float* __restrict__ x,
                                               const float* __restrict__ W1,
                                               const float* __restrict__ b1,
                                               double* __restrict__ yd) {
    __shared__ double Wl[96 * 48];
    int tid = threadIdx.x;
    int rl = tid & 255, h = tid >> 8;
    int dbase = blockIdx.y * 48;
    for (int q = tid; q < 96 * 48; q += 512) {
        int c = q / 48, dd = q % 48;
        Wl[c * 48 + dd] = (double)W1[c * 96 + dbase + dd];
    }
    __syncthreads();
    int r = blockIdx.x * 256 + rl;
    int b = r / N_;
    int n = r - b * N_;
    double acc[24];
#pragma unroll
    for (int i = 0; i < 24; i++) acc[i] = 0.0;
    const float* xp = x + (size_t)b * C_ * N_ + n;
    for (int c = 0; c < 96; ++c) {
        double xv = (double)xp[(size_t)c * N_];
        const double* w = &Wl[c * 48 + h * 24];
#pragma unroll
        for (int i = 0; i < 24; ++i) acc[i] += xv * w[i];
    }
    int d0 = dbase + h * 24;
#pragma unroll
    for (int i = 0; i < 24; i++) {
        int d = d0 + i;
        yd[((size_t)b * C_ + d) * N_ + n] = acc[i] + (double)b1[d];
    }
}

// ---------------- fp64 per-channel stats over yd ----------------
__global__ __launch_bounds__(256) void k_stats_chan_d(const double* __restrict__ src,
                                                      double* __restrict__ partial) {
    int c = blockIdx.x;
    int chunk = blockIdx.y;
    const int SPLIT = 16;
    double s = 0.0, ss = 0.0;
    for (int j = chunk * 256 + threadIdx.x; j < R_; j += SPLIT * 256) {
        int b = j / N_, n = j - b * N_;
        double v = src[((size_t)b * C_ + c) * N_ + n];
        s += v;
        ss += v * v;
    }
    __shared__ double red[8];
    for (int off = 32; off; off >>= 1) {
        s += __shfl_down(s, off, 64);
        ss += __shfl_down(ss, off, 64);
    }
    int lane = threadIdx.x & 63, w = threadIdx.x >> 6;
    if (lane == 0) { red[w * 2] = s; red[w * 2 + 1] = ss; }
    __syncthreads();
    if (threadIdx.x == 0) {
        s = red[0] + red[2] + red[4] + red[6];
        ss = red[1] + red[3] + red[5] + red[7];
        partial[(c * SPLIT + chunk) * 2] = s;
        partial[(c * SPLIT + chunk) * 2 + 1] = ss;
    }
}

__global__ void k_stats_reduce_d(const double* __restrict__ partial, double* __restrict__ stats) {
    int c = blockIdx.x * blockDim.x + threadIdx.x;
    if (c >= 96) return;
    double s = 0.0, ss = 0.0;
    for (int k = 0; k < 16; k++) {
        s += partial[(c * 16 + k) * 2];
        ss += partial[(c * 16 + k) * 2 + 1];
    }
    double m = s / (double)R_;
    double var = ss / (double)R_ - m * m;
    stats[c * 2] = m;
    stats[c * 2 + 1] = 1.0 / sqrt(var + 1e-5);
}

// ---------------- fp32 per-channel stats (interleaved partial layout) ----------------
__global__ void k_stats_reduce(const float* __restrict__ partial, float* __restrict__ stats,
                               int Cn, int SPLIT, float invcount) {
    int c = blockIdx.x * blockDim.x + threadIdx.x;
    if (c >= Cn) return;
    float s = 0.f, ss = 0.f;
    for (int k = 0; k < SPLIT; k++) {
        s += partial[(c * SPLIT + k) * 2];
        ss += partial[(c * SPLIT + k) * 2 + 1];
    }
    float m = s * invcount;
    float var = ss * invcount - m * m;
    stats[c * 2] = m;
    stats[c * 2 + 1] = 1.0f / sqrtf(var + EPS_);
}

// generalized block-partial reducer: partial[k*2*Cn + c] (sum), [k*2*Cn + Cn + c] (ss)
__global__ __launch_bounds__(256) void k_stats_reduce_g(const float* __restrict__ partial,
                                                        float* __restrict__ stats,
                                                        int Cn, int NB, float invcount) {
    int c = blockIdx.x;      // 0..Cn-1
    float s = 0.f, ss = 0.f;
    for (int k = threadIdx.x; k < NB; k += 256) {
        s  += partial[(size_t)k * 2 * Cn + c];
        ss += partial[(size_t)k * 2 * Cn + Cn + c];
    }
    __shared__ float red[8];
    for (int off = 32; off; off >>= 1) {
        s += __shfl_down(s, off, 64);
        ss += __shfl_down(ss, off, 64);
    }
    int lane = threadIdx.x & 63, w = threadIdx.x >> 6;
    if (lane == 0) { red[w * 2] = s; red[w * 2 + 1] = ss; }
    __syncthreads();
    if (threadIdx.x == 0) {
        s = red[0] + red[2] + red[4] + red[6];
        ss = red[1] + red[3] + red[5] + red[7];
        float m = s * invcount;
        float var = ss * invcount - m * m;
        stats[c * 2] = m;
        stats[c * 2 + 1] = 1.0f / sqrtf(var + EPS_);
    }
}

// ---------------- BN1 apply + LDS transpose; also zeroes poolCnt ----------------
__global__ __launch_bounds__(256) void k_bn1_tr(const double* __restrict__ yd,
                                                const double* __restrict__ stats,
                                                const float* __restrict__ g,
                                                const float* __restrict__ be,
                                                float* __restrict__ ftc,
                                                double* __restrict__ ftp64,
                                                unsigned short* __restrict__ fspH,
                                                double* __restrict__ sq64,
                                                unsigned* __restrict__ poolCnt) {
    __shared__ double tile[64 * 97];     // [point][chan], stride 97
    __shared__ double dsq[64][4];
    int b = blockIdx.y;
    int n0 = blockIdx.x * 64;
    int tid = threadIdx.x;
    int n = tid & 63, w = tid >> 6;
    for (int k = 0; k < 24; ++k) {
        int c = k * 4 + w;
        size_t gi = ((size_t)b * C_ + c) * N_ + n0 + n;
        double m = stats[c * 2], rs = stats[c * 2 + 1];
        double v = (double)g[c] * (yd[gi] - m) * rs + (double)be[c];
        ftc[gi] = (float)v;
        tile[n * 97 + c] = v;
    }
    __syncthreads();
    int p = n, q = w;
    double vals[24];
    double s = 0.0;
    const double* lp = &tile[p * 97 + q * 24];
#pragma unroll
    for (int m2 = 0; m2 < 24; ++m2) { vals[m2] = lp[m2]; s += vals[m2] * vals[m2]; }
    dsq[p][q] = s;
    double* dst = ftp64 + ((size_t)b * N_ + n0 + p) * C_ + q * 24;
#pragma unroll
    for (int m2 = 0; m2 < 24; m2 += 2) *(double2*)&dst[m2] = make_double2(vals[m2], vals[m2 + 1]);
    unsigned* hdst = (unsigned*)(fspH + ((size_t)b * N_ + n0 + p) * QS2);
#pragma unroll
    for (int m2 = 0; m2 < 24; m2 += 2) {
        unsigned u0 = __float_as_uint((float)vals[m2]);
        unsigned u1 = __float_as_uint((float)vals[m2 + 1]);
        unsigned h0 = (u0 + 0x7fffu + ((u0 >> 16) & 1u)) >> 16;      // RNE to bf16
        unsigned h1 = (u1 + 0x7fffu + ((u1 >> 16) & 1u)) >> 16;
        hdst[q * 12 + (m2 >> 1)] = h0 | (h1 << 16);
    }
    __syncthreads();
    if (tid < 64) {
        double tot = dsq[tid][0] + dsq[tid][1] + dsq[tid][2] + dsq[tid][3];
        sq64[(size_t)b * N_ + n0 + tid] = tot;
        poolCnt[(size_t)b * N_ + n0 + tid] = 0u;
        float t32 = (float)(-0.5 * tot);
        unsigned u0 = __float_as_uint(t32);
        unsigned h0 = (u0 + 0x7fffu + ((u0 >> 16) & 1u)) >> 16;
        float resid = t32 - __uint_as_float(h0 << 16);
        unsigned u1 = __float_as_uint(resid);
        unsigned h1 = (u1 + 0x7fffu + ((u1 >> 16) & 1u)) >> 16;
        unsigned* hd = (unsigned*)(fspH + ((size_t)b * N_ + n0 + tid) * QS2);
        hd[48] = h0 | (h1 << 16);
#pragma unroll
        for (int k2 = 49; k2 < 64; ++k2) hd[k2] = 0u;
    }
}

// ---------------- fused per-half two-pass dist: 64 queries x half the candidates ----------------
// grid (49, 2, 8); 4 waves. pass 0: f32 chunk-minima in LDS -> per-half t9 (valid bound: a global
// top-9 member is also top-9 within its half); pass 1: compact d<=t9+margin via global atomics.
__global__ __launch_bounds__(256) void k_dist5(const unsigned short* __restrict__ fspH,
                                               unsigned short* __restrict__ poolC,
                                               unsigned* __restrict__ poolCnt) {
    __shared__ __align__(16) char lds[39680];
    // buf0 [0,16384) | buf1 [16384,32768) | cminF [32768,39168) 25*64 f32 | t9fL [39168,39424)
    float* cminF = (float*)(lds + 32768);
    float* t9fL  = (float*)(lds + 39168);
    int b = blockIdx.z, half = blockIdx.y;
    int q0 = blockIdx.x * 64;
    int tid = threadIdx.x, w = tid >> 6, l = tid & 63;
    int ch0 = half * 25, nch = half ? 24 : 25;
    int qg = b * N_ + q0 + w * 16 + (l & 15);

    // stage queries into buf0 (swizzled), load query B-frags (+norm slice) to registers
    {
        const uint4* src = (const uint4*)(fspH + ((size_t)b * N_ + q0) * QS2);
        uint4* dst = (uint4*)lds;
        for (int i = tid; i < 1024; i += 256) dst[swz16(i)] = src[i];
    }
    __syncthreads();
    bf16x8 Bq[4];
    {
        const unsigned short* Ql = (const unsigned short*)lds;
        int qr = w * 16 + (l & 15);
#pragma unroll
        for (int s = 0; s < 3; ++s) {
            int col = (s * 4 + (l >> 4)) ^ (qr & 7);
            Bq[s] = *(const bf16x8*)&Ql[qr * QS2 + col * 8];
        }
        bf16x8 z = {0, 0, 0, 0, 0, 0, 0, 0};
        if ((l >> 4) == 0) { z[0] = (short)0x3F80; z[1] = (short)0x3F80; }   // bf16 1.0
        Bq[3] = z;
    }
    __syncthreads();   // buf0 free

    // prologue: stage chunk ch0 into buf0
    {
        const uint4* src = (const uint4*)(fspH + ((size_t)b * N_ + ch0 * 64) * QS2);
        uint4* dst = (uint4*)lds;
        for (int i = tid; i < 1024; i += 256) dst[swz16(i)] = src[i];
    }
    __syncthreads();

    float thr2r = 1e30f;     // acc-space threshold (acc >= thr2r), set after pass 0
    int cur = 0;
    int nct = 2 * nch;
    for (int t = 0; t < nct; ++t) {
        int chl = (t < nch) ? t : t - nch;
        int c0 = (ch0 + chl) * 64;
        bool pf = (t < nct - 1);
        uint4 st0, st1, st2, st3;
        if (pf) {
            int tn = t + 1;
            int nc = ch0 + ((tn < nch) ? tn : tn - nch);
            const uint4* src = (const uint4*)(fspH + ((size_t)b * N_ + nc * 64) * QS2);
            st0 = src[tid]; st1 = src[tid + 256]; st2 = src[tid + 512]; st3 = src[tid + 768];
        }
        const unsigned short* Bc = (const unsigned short*)(lds + cur * 16384);
        f32x4 acc[4];
#pragma unroll
        for (int ct = 0; ct < 4; ++ct) acc[ct] = (f32x4){0.f, 0.f, 0.f, 0.f};
#pragma unroll
        for (int s = 0; s < 4; ++s) {
#pragma unroll
            for (int ct = 0; ct < 4; ++ct) {
                int cr = ct * 16 + (l & 15);
                int col = (s * 4 + (l >> 4)) ^ (cr & 7);
                bf16x8 Ac = *(const bf16x8*)&Bc[cr * QS2 + col * 8];
                acc[ct] = __builtin_amdgcn_mfma_f32_16x16x32_bf16(Ac, Bq[s], acc[ct], 0, 0, 0);
            }
        }
        if (t < nch) {
            float mx = -1e30f;
#pragma unroll
            for (int ct = 0; ct < 4; ++ct)
#pragma unroll
                for (int j = 0; j < 4; ++j) mx = fmaxf(mx, acc[ct][j]);
            mx = fmaxf(mx, __shfl_xor(mx, 16, 64));
            mx = fmaxf(mx, __shfl_xor(mx, 32, 64));
            if (l < 16) cminF[chl * 64 + w * 16 + l] = -2.f * mx;
        } else {
#pragma unroll
            for (int ct = 0; ct < 4; ++ct)
#pragma unroll
                for (int j = 0; j < 4; ++j) {
                    if (acc[ct][j] >= thr2r) {                       // rare
                        unsigned pos = atomicAdd(&poolCnt[qg], 1u);
                        if (pos < (unsigned)CAP3)
                            poolC[(size_t)qg * CAP3 + pos] = (unsigned short)(c0 + ct * 16 + (l >> 4) * 4 + j);
                    }
                }
        }
        if (t == nch - 1) {
            __syncthreads();     // all cmin written
            if (tid < 64) {
                float top[9];
#pragma unroll
                for (int j = 0; j < 9; ++j) top[j] = 1e30f;
                for (int q = 0; q < nch; ++q) {
                    float v = cminF[q * 64 + tid];
                    if (v < top[8]) {
                        top[8] = v;
#pragma unroll
                        for (int j = 8; j >= 1; --j)
                            if (top[j] < top[j - 1]) { float tt = top[j]; top[j] = top[j - 1]; top[j - 1] = tt; }
                    }
                }
                float t9 = top[8] + fabsf(top[8]) * 0.008f + 0.75f;  // hi-bf16 error margin
                t9fL[tid] = -0.5f * t9;                              // acc-space
            }
            __syncthreads();
            thr2r = t9fL[w * 16 + (l & 15)];
        }
        if (pf) {
            uint4* dst = (uint4*)(lds + (cur ^ 1) * 16384);
            dst[swz16(tid)] = st0;
            dst[swz16(tid + 256)] = st1;
            dst[swz16(tid + 512)] = st2;
            dst[swz16(tid + 768)] = st3;
        }
        __syncthreads();
        cur ^= 1;
    }
}

// ---------------- fp64 exact re-rank of variable pool -> top-9 set ----------------
__global__ __launch_bounds__(256) void k_rerank_d(const unsigned short* __restrict__ poolC,
                                                  const unsigned* __restrict__ poolCnt,
                                                  const double* __restrict__ ftp64,
                                                  const double* __restrict__ sq64,
                                                  int* __restrict__ idx) {
    int tid = threadIdx.x;
    int wv = tid >> 6, l = tid & 63;
    int rr = blockIdx.x * 4 + wv;
    int b = rr / N_;
    int cnt = (int)poolCnt[rr];
    if (cnt > CAP3) cnt = CAP3;
    int e = l & 3;
    double qreg[24];
    {
        const double* qb = ftp64 + (size_t)rr * C_ + e * 24;
#pragma unroll
        for (int m = 0; m < 24; ++m) qreg[m] = qb[m];
    }
    double dv[4];
    int jv[4];
#pragma unroll
    for (int gG = 0; gG < 4; ++gG) { dv[gG] = 1e300; jv[gG] = 0x7fffffff; }
#pragma unroll
    for (int gG = 0; gG < 4; ++gG) {
        if (gG * 16 >= cnt) break;                 // wave-uniform skip
        int ci = gG * 16 + (l >> 2);
        bool valid = ci < cnt;
        int j = valid ? (int)poolC[(size_t)rr * CAP3 + ci] : 0;
        const double* cb = ftp64 + ((size_t)b * N_ + j) * C_ + e * 24;
        double p = 0.0;
#pragma unroll
        for (int m = 0; m < 24; ++m) p += qreg[m] * cb[m];
        p += __shfl_xor(p, 1, 64);
        p += __shfl_xor(p, 2, 64);
        if (valid) {
            dv[gG] = sq64[(size_t)b * N_ + j] - 2.0 * p;
            jv[gG] = j;
        }
    }
#pragma unroll
    for (int r = 0; r < 9; ++r) {
        double dm = dv[0]; int jm = jv[0];
#pragma unroll
        for (int gG = 1; gG < 4; ++gG)
            if (dv[gG] < dm || (dv[gG] == dm && jv[gG] < jm)) { dm = dv[gG]; jm = jv[gG]; }
#pragma unroll
        for (int off = 1; off <= 32; off <<= 1) {
            double od = __shfl_xor(dm, off, 64);
            int oj = __shfl_xor(jm, off, 64);
            if (od < dm || (od == dm && oj < jm)) { dm = od; jm = oj; }
        }
        if (l == 0) idx[(size_t)rr * 9 + r] = jm;
#pragma unroll
        for (int gG = 0; gG < 4; ++gG)
            if (jv[gG] == jm) dv[gG] = 1e300;
    }
}

// ---------------- fused: u = ft·(Wtop-Wbot)+b_edge AND v = ft·Wbot ----------------
__global__ __launch_bounds__(512) void k_gemm_uv2(const float* __restrict__ ftc,
                                                  const float* __restrict__ We,
                                                  const float* __restrict__ beb,
                                                  float* __restrict__ u,
                                                  float* __restrict__ v) {
    __shared__ float Wl[2][96 * 48];
    int tid = threadIdx.x;
    int rl = tid & 255, h = tid >> 8;
    int dbase = blockIdx.y * 48;
    for (int q = tid; q < 96 * 48; q += 512) {
        int c = q / 48, dd = q % 48;
        float wb = We[(96 + c) * C2_ + dbase + dd];
        Wl[1][q] = wb;
        Wl[0][q] = We[c * C2_ + dbase + dd] - wb;
    }
    __syncthreads();
    int r = blockIdx.x * 256 + rl;
    int b = r / N_, n = r - b * N_;
    float a0[24], a1[24];
#pragma unroll
    for (int i = 0; i < 24; i++) { a0[i] = 0.f; a1[i] = 0.f; }
    const float* xp = ftc + (size_t)b * C_ * N_ + n;
    for (int c = 0; c < 96; ++c) {
        float xv = xp[(size_t)c * N_];
        const float4* w40 = (const float4*)&Wl[0][c * 48 + h * 24];
        const float4* w41 = (const float4*)&Wl[1][c * 48 + h * 24];
#pragma unroll
        for (int i = 0; i < 6; ++i) {
            float4 w0 = w40[i], w1 = w41[i];
            a0[i * 4 + 0] += xv * w0.x; a0[i * 4 + 1] += xv * w0.y;
            a0[i * 4 + 2] += xv * w0.z; a0[i * 4 + 3] += xv * w0.w;
            a1[i * 4 + 0] += xv * w1.x; a1[i * 4 + 1] += xv * w1.y;
            a1[i * 4 + 2] += xv * w1.z; a1[i * 4 + 3] += xv * w1.w;
        }
    }
    int d0 = dbase + h * 24;
    float* up = u + (size_t)r * C2_ + d0;
    float* vp = v + (size_t)r * C2_ + d0;
#pragma unroll
    for (int i = 0; i < 6; ++i) {
        float4 ou, ov;
        ou.x = a0[i * 4 + 0] + beb[d0 + i * 4 + 0];
        ou.y = a0[i * 4 + 1] + beb[d0 + i * 4 + 1];
        ou.z = a0[i * 4 + 2] + beb[d0 + i * 4 + 2];
        ou.w = a0[i * 4 + 3] + beb[d0 + i * 4 + 3];
        ov.x = a1[i * 4 + 0]; ov.y = a1[i * 4 + 1];
        ov.z = a1[i * 4 + 2]; ov.w = a1[i * 4 + 3];
        ((float4*)up)[i] = ou;
        ((float4*)vp)[i] = ov;
    }
}

// ---------------- edge-BN stats: e = u[n,d] + v[j,d] over all (row,k) ----------------
__global__ __launch_bounds__(192) void k_bne_stats(const float* __restrict__ u,
                                                   const float* __restrict__ v,
                                                   const int* __restrict__ idx,
                                                   float* __restrict__ partial) {
    int d = threadIdx.x;
    int row0 = blockIdx.x * 32;
    int b = row0 / N_;
    float s = 0.f, ss = 0.f;
    for (int r = 0; r < 32; ++r) {
        int row = row0 + r;
        float ud = u[(size_t)row * C2_ + d];
        const int* ip = idx + (size_t)row * 9;
#pragma unroll
        for (int k = 0; k < 9; k++) {
            int j = ip[k];
            float e = ud + v[((size_t)b * N_ + j) * C2_ + d];
            s += e;
            ss += e * e;
        }
    }
    partial[(size_t)blockIdx.x * 384 + d] = s;
    partial[(size_t)blockIdx.x * 384 + 192 + d] = ss;
}

// ---------------- edge BN+relu+max over k, fc2 (192->96), fused out2 stats ----------------
__global__ __launch_bounds__(192) void k_edge_fc2_st(const float* __restrict__ u,
                                                     const float* __restrict__ v,
                                                     const int* __restrict__ idx,
                                                     const float* __restrict__ statsE,
                                                     const float* __restrict__ ge,
                                                     const float* __restrict__ bee,
                                                     const float* __restrict__ W2,
                                                     const float* __restrict__ b2,
                                                     float* __restrict__ out2,
                                                     float* __restrict__ partialE) {
    __shared__ float gl[16][C2_];
    __shared__ float g2[C_][16];
    int tid = threadIdx.x;
    int row0 = blockIdx.x * 16;
    int b = row0 / N_;
    int n0 = row0 - b * N_;
    {
        int d = tid;
        float m = statsE[d * 2], rs = statsE[d * 2 + 1];
        float ga = ge[d], bb = bee[d];
        for (int r = 0; r < 16; ++r) {
            int row = row0 + r;
            float ud = u[(size_t)row * C2_ + d];
            const int* ip = idx + (size_t)row * 9;
            float gm = 0.f;                      // relu-then-max == max with 0
#pragma unroll
            for (int k = 0; k < 9; k++) {
                int j = ip[k];
                float e = ud + v[((size_t)b * N_ + j) * C2_ + d];
                float val = ga * (e - m) * rs + bb;
                gm = fmaxf(gm, val);
            }
            gl[r][d] = gm;
        }
    }
    __syncthreads();
    {
        int rr = tid / 24;
        int dq = tid % 24;
        for (int rep = 0; rep < 2; ++rep) {
            int r = rr + rep * 8;
            float4 acc = *(const float4*)&b2[dq * 4];
            for (int d = 0; d < C2_; ++d) {
                float gv = gl[r][d];
                float4 w = *(const float4*)&W2[d * C_ + dq * 4];
                acc.x += gv * w.x;
                acc.y += gv * w.y;
                acc.z += gv * w.z;
                acc.w += gv * w.w;
            }
            g2[dq * 4 + 0][r] = acc.x;
            g2[dq * 4 + 1][r] = acc.y;
            g2[dq * 4 + 2][r] = acc.z;
            g2[dq * 4 + 3][r] = acc.w;
        }
    }
    __syncthreads();
    for (int q = tid; q < 96 * 4; q += 192) {
        int dd = q / 4, part = q % 4;
        float4 val = *(const float4*)&g2[dd][part * 4];
        *(float4*)&out2[((size_t)b * C_ + dd) * N_ + n0 + part * 4] = val;
    }
    // fused out2 stats: thread pair (2c, 2c+1) covers channel c
    {
        int c = tid >> 1, h = tid & 1;
        float s = 0.f, ss = 0.f;
#pragma unroll
        for (int r = 0; r < 8; ++r) {
            float vv = g2[c][h * 8 + r];
            s += vv;
            ss += vv * vv;
        }
        s += __shfl_xor(s, 1, 64);
        ss += __shfl_xor(ss, 1, 64);
        if (h == 0) {
            partialE[(size_t)blockIdx.x * 192 + c] = s;
            partialE[(size_t)blockIdx.x * 192 + 96 + c] = ss;
        }
    }
}

// ---------------- t = bn2(out2) + x, with fused per-channel stats of t ----------------
__global__ __launch_bounds__(256) void k_bn2_add_st(const float* __restrict__ out2,
                                                    const float* __restrict__ x,
                                                    const float* __restrict__ stats,
                                                    const float* __restrict__ g,
                                                    const float* __restrict__ be,
                                                    float* __restrict__ t,
                                                    float* __restrict__ partial) {
    int c = blockIdx.x;
    int chunk = blockIdx.y;
    const int SPLIT = 16;
    float m = stats[c * 2], rs = stats[c * 2 + 1];
    float ga = g[c], bb = be[c];
    float s = 0.f, ss = 0.f;
    for (int j = chunk * 256 + threadIdx.x; j < R_; j += SPLIT * 256) {
        int b = j / N_, n = j - b * N_;
        size_t i = ((size_t)b * C_ + c) * N_ + n;
        float tv = ga * (out2[i] - m) * rs + bb + x[i];
        t[i] = tv;
        s += tv;
        ss += tv * tv;
    }
    __shared__ float red[8];
    for (int off = 32; off; off >>= 1) {
        s += __shfl_down(s, off, 64);
        ss += __shfl_down(ss, off, 64);
    }
    int lane = threadIdx.x & 63, w = threadIdx.x >> 6;
    if (lane == 0) { red[w * 2] = s; red[w * 2 + 1] = ss; }
    __syncthreads();
    if (threadIdx.x == 0) {
        s = red[0] + red[2] + red[4] + red[6];
        ss = red[1] + red[3] + red[5] + red[7];
        partial[(c * SPLIT + chunk) * 2] = s;
        partial[(c * SPLIT + chunk) * 2 + 1] = ss;
    }
}

// ---------------- conv 3x3 s2 p1, 96->192, inline sabn+relu on input, fused z stats ----------------
__global__ __launch_bounds__(256) void k_conv8(const float* __restrict__ t,
                                               const float* __restrict__ statsS,
                                               const float* __restrict__ gS,
                                               const float* __restrict__ beS,
                                               const float* __restrict__ Wd,
                                               const float* __restrict__ bd,
                                               float* __restrict__ z,
                                               float* __restrict__ partialD) {
    __shared__ float Wl[96 * 9 * 8];
    __shared__ float scl[96], shf[96];
    __shared__ float redc[4][16];
    int b = blockIdx.z;
    int oc0 = blockIdx.y * 8;
    int p = blockIdx.x * 256 + threadIdx.x;
    for (int i = threadIdx.x; i < 96 * 9 * 8; i += 256) {
        int oc = i & 7, icq = i >> 3;
        Wl[i] = Wd[(size_t)(oc0 + oc) * 864 + icq];
    }
    if (threadIdx.x < 96) {
        int c = threadIdx.x;
        float m = statsS[c * 2], rs = statsS[c * 2 + 1], ga = gS[c];
        scl[c] = ga * rs;
        shf[c] = beS[c] - ga * m * rs;
    }
    __syncthreads();
    bool valid = p < NO_;
    int oh = valid ? p / HO_ : 0, ow = valid ? p % HO_ : 0;
    float acc[8];
#pragma unroll
    for (int i = 0; i < 8; i++) acc[i] = 0.f;
    int ih0 = oh * 2 - 1, iw0 = ow * 2 - 1;
    const float* tb = t + (size_t)b * C_ * N_;
    for (int ic = 0; ic < 96; ++ic) {
        const float* sp = tb + (size_t)ic * N_;
        float sc_ = scl[ic], sh_ = shf[ic];
        float in[9];
#pragma unroll
        for (int kh = 0; kh < 3; kh++) {
            int ih = ih0 + kh;
            bool okh = valid && ((unsigned)ih < 56u);
#pragma unroll
            for (int kw = 0; kw < 3; kw++) {
                int iw = iw0 + kw;
                bool ok = okh && ((unsigned)iw < 56u);
                float raw = ok ? sp[ih * 56 + iw] : 0.f;
                in[kh * 3 + kw] = ok ? fmaxf(sc_ * raw + sh_, 0.f) : 0.f;
            }
        }
#pragma unroll
        for (int q = 0; q < 9; q++) {
            float iv = in[q];
            const float4* w4 = (const float4*)&Wl[(ic * 9 + q) * 8];
#pragma unroll
            for (int j = 0; j < 2; j++) {
                float4 w = w4[j];
                acc[j * 4 + 0] += iv * w.x;
                acc[j * 4 + 1] += iv * w.y;
                acc[j * 4 + 2] += iv * w.z;
                acc[j * 4 + 3] += iv * w.w;
            }
        }
    }
    float s8[8];
#pragma unroll
    for (int i = 0; i < 8; i++) {
        float ov = acc[i] + bd[oc0 + i];
        if (valid) z[((size_t)b * OUP_ + oc0 + i) * NO_ + p] = ov;
        s8[i] = valid ? ov : 0.f;
    }
    int w = threadIdx.x >> 6;
#pragma unroll
    for (int i = 0; i < 8; ++i) {
        float s = s8[i], ss = s8[i] * s8[i];
        for (int off = 32; off; off >>= 1) {
            s += __shfl_down(s, off, 64);
            ss += __shfl_down(ss, off, 64);
        }
        if ((threadIdx.x & 63) == 0) { redc[w][i * 2] = s; redc[w][i * 2 + 1] = ss; }
    }
    __syncthreads();
    if (threadIdx.x < 16) {
        float v = redc[0][threadIdx.x] + redc[1][threadIdx.x] + redc[2][threadIdx.x] + redc[3][threadIdx.x];
        int blk = (b * 24 + blockIdx.y) * 4 + blockIdx.x;
        partialD[blk * 16 + threadIdx.x] = v;
    }
}

// reduce conv partials: channel c -> 32 blocks (8 b x 4 x-tiles)
__global__ void k_stats_reduce_conv(const float* __restrict__ partialD, float* __restrict__ stats) {
    int c = threadIdx.x;
    if (c >= 192) return;
    int y = c >> 3, o = c & 7;
    float s = 0.f, ss = 0.f;
    for (int bb = 0; bb < 8; ++bb)
        for (int x2 = 0; x2 < 4; ++x2) {
            int blk = (bb * 24 + y) * 4 + x2;
            s += partialD[blk * 16 + o * 2];
            ss += partialD[blk * 16 + o * 2 + 1];
        }
    float m = s / 6272.f;
    float var = ss / 6272.f - m * m;
    stats[c * 2] = m;
    stats[c * 2 + 1] = 1.0f / sqrtf(var + EPS_);
}

// ---------------- out = relu(dwbn(z)) ----------------
__global__ __launch_bounds__(256) void k_out(const float* __restrict__ z,
                                             const float* __restrict__ stats,
                                             const float* __restrict__ g,
                                             const float* __restrict__ be,
                                             float* __restrict__ out) {
    int i = blockIdx.x * 256 + threadIdx.x;
    if (i >= B_ * OUP_ * NO_) return;
    int c = (i / NO_) % OUP_;
    out[i] = fmaxf(g[c] * (z[i] - stats[c * 2]) * stats[c * 2 + 1] + be[c], 0.f);
}

extern "C" void kernel_launch(void* const* d_in, const int* in_sizes, int n_in,
                              void* d_out, int out_size, void* d_ws, size_t ws_size,
                              hipStream_t stream) {
    const float* x     = (const float*)d_in[0];
    const float* W_fc1 = (const float*)d_in[1];
    const float* b_fc1 = (const float*)d_in[2];
    const float* g_bn1 = (const float*)d_in[3];
    const float* be_bn1= (const float*)d_in[4];
    const float* W_edge= (const float*)d_in[5];
    const float* b_edge= (const float*)d_in[6];
    const float* g_bne = (const float*)d_in[7];
    const float* be_bne= (const float*)d_in[8];
    const float* W_fc2 = (const float*)d_in[9];
    const float* b_fc2 = (const float*)d_in[10];
    const float* g_bn2 = (const float*)d_in[11];
    const float* be_bn2= (const float*)d_in[12];
    const float* g_sabn= (const float*)d_in[13];
    const float* be_sabn=(const float*)d_in[14];
    const float* W_dw  = (const float*)d_in[15];
    const float* b_dw  = (const float*)d_in[16];
    const float* g_dwbn= (const float*)d_in[17];
    const float* be_dwbn=(const float*)d_in[18];

    // byte-offset workspace layout with lifetime-based aliasing (~74.8 MB)
    char* base = (char*)d_ws;
    float*  ftc   = (float*)(base + 0);                    //  9,633,792 [bn1_tr -> gemm]; then tbuf alias below uses other region
    double* ftp64 = (double*)(base + 9633792);             // 19,267,584 [bn1_tr -> rerank]; then uu
    float*  uu    = (float*)(base + 9633792);
    double* yd    = (double*)(base + 28901376);            // 19,267,584 [fc1 -> bn1_tr]; then vv
    float*  vv    = (float*)(base + 28901376);
    unsigned short* fspH = (unsigned short*)(base + 48168960); // 6,422,528 [bn1_tr -> dist]; then out2
    float*  out2  = (float*)(base + 48168960);
    unsigned short* poolC = (unsigned short*)(base + 57802752); // 3,211,264 [dist -> rerank]; then tbuf
    float*  tbuf  = (float*)(base + 57802752);             //  9,633,792 [bn2 -> conv8]
    double* sq64  = (double*)(base + 67436544);            //    200,704
    int*    idx   = (int*)(base + 67637248);               //    903,168 [rerank -> edge]
    unsigned* poolCnt = (unsigned*)(base + 68540416);      //    100,352
    float*  partial = (float*)(base + 68741120);           //  1,204,224 max (bne/partialE/bn2/partialD reuse)
    double* partiald = (double*)(base + 68741120);         //     24,576 (earliest use, same region)
    double* stats1d = (double*)(base + 69945344);          //      1,536
    float*  statsE  = (float*)(base + 69946880);
    float*  stats2  = (float*)(base + 69948416);
    float*  statsS  = (float*)(base + 69949952);
    float*  statsD  = (float*)(base + 69951488);
    float*  zbuf  = (float*)(base + 69953024);             //  4,816,896 [conv -> out] -> ends 74,769,920

    // fc1 + BN1 (fp64 path); bn1_tr fuses apply+transpose+bf16-split+norm-fold+sqrows+poolCnt-zero
    k_fc1_d<<<dim3(98, 2), 512, 0, stream>>>(x, W_fc1, b_fc1, yd);
    k_stats_chan_d<<<dim3(96, 16), 256, 0, stream>>>(yd, partiald);
    k_stats_reduce_d<<<1, 256, 0, stream>>>(partiald, stats1d);
    k_bn1_tr<<<dim3(49, B_), 256, 0, stream>>>(yd, stats1d, g_bn1, be_bn1, ftc, ftp64, fspH, sq64, poolCnt);

    // kNN: fused per-half two-pass MFMA dist (784 blocks), then fp64 re-rank -> exact top-9
    k_dist5<<<dim3(49, 2, B_), 256, 0, stream>>>(fspH, poolC, poolCnt);
    k_rerank_d<<<6272, 256, 0, stream>>>(poolC, poolCnt, ftp64, sq64, idx);

    // fused edge GEMMs: u = ft·(Wtop-Wbot)+b_edge, v = ft·Wbot (overwrite ftp64/yd)
    k_gemm_uv2<<<dim3(98, 4), 512, 0, stream>>>(ftc, W_edge, b_edge, uu, vv);

    // edge BN stats, then BN+relu+max+fc2 with fused out2 stats
    k_bne_stats<<<784, 192, 0, stream>>>(uu, vv, idx, partial);
    k_stats_reduce_g<<<192, 256, 0, stream>>>(partial, statsE, 192, 784, 1.0f / 225792.0f);
    k_edge_fc2_st<<<1568, 192, 0, stream>>>(uu, vv, idx, statsE, g_bne, be_bne, W_fc2, b_fc2, out2, partial);
    k_stats_reduce_g<<<96, 256, 0, stream>>>(partial, stats2, 96, 1568, 1.0f / (float)R_);

    // BN2 + shortcut (stats of t fused)
    k_bn2_add_st<<<dim3(96, 16), 256, 0, stream>>>(out2, x, stats2, g_bn2, be_bn2, tbuf, partial);
    k_stats_reduce<<<1, 256, 0, stream>>>(partial, statsS, 96, 16, 1.0f / (float)R_);

    // conv (inline sabn+relu, fused z stats) + dwbn + relu
    k_conv8<<<dim3(4, 24, 8), 256, 0, stream>>>(tbuf, statsS, g_sabn, be_sabn, W_dw, b_dw, zbuf, partial);
    k_stats_reduce_conv<<<1, 192, 0, stream>>>(partial, statsD);
    k_out<<<4705, 256, 0, stream>>>(zbuf, statsD, g_dwbn, be_dwbn, (float*)d_out);
}

// Round 12
// 685.924 us; speedup vs baseline: 1.0092x; 1.0092x over previous
//
#include <hip/hip_runtime.h>
#include <math.h>

#define B_   8
#define C_   96
#define C2_  192
#define N_   3136        // 56*56
#define R_   25088       // B_*N_
#define OUP_ 192
#define HO_  28
#define NO_  784         // 28*28
#define EPS_ 1e-5f
#define QS2  128         // fspH point stride in u16 (256 B); ch 96/97 = split(-sq/2), 98-127 zero
#define CAP3 64          // per-row candidate pool cap

typedef short bf16x8 __attribute__((ext_vector_type(8)));
typedef float f32x4  __attribute__((ext_vector_type(4)));

// uint4-slot XOR swizzle within a 64-row x 16-slot tile (T2): col ^= row&7
__device__ __forceinline__ int swz16(int i) { return (i & ~15) | ((i & 15) ^ ((i >> 4) & 7)); }

// ---------------- fc1 (fp64 accumulate): yd[b,d,n] = sum_c x[b,c,n]*W1[c,d] + b1[d] ----------------
__global__ __launch_bounds__(512) void k_fc1_d(const float* __restrict__ x,
                                               const float* __restrict__ W1,
                                               const float* __restrict__ b1,
                                               double* __restrict__ yd) {
    __shared__ double Wl[96 * 48];
    int tid = threadIdx.x;
    int rl = tid & 255, h = tid >> 8;
    int dbase = blockIdx.y * 48;
    for (int q = tid; q < 96 * 48; q += 512) {
        int c = q / 48, dd = q % 48;
        Wl[c * 48 + dd] = (double)W1[c * 96 + dbase + dd];
    }
    __syncthreads();
    int r = blockIdx.x * 256 + rl;
    int b = r / N_;
    int n = r - b * N_;
    double acc[24];
#pragma unroll
    for (int i = 0; i < 24; i++) acc[i] = 0.0;
    const float* xp = x + (size_t)b * C_ * N_ + n;
    for (int c = 0; c < 96; ++c) {
        double xv = (double)xp[(size_t)c * N_];
        const double* w = &Wl[c * 48 + h * 24];
#pragma unroll
        for (int i = 0; i < 24; ++i) acc[i] += xv * w[i];
    }
    int d0 = dbase + h * 24;
#pragma unroll
    for (int i = 0; i < 24; i++) {
        int d = d0 + i;
        yd[((size_t)b * C_ + d) * N_ + n] = acc[i] + (double)b1[d];
    }
}

// ---------------- fp64 per-channel stats over yd ----------------
__global__ __launch_bounds__(256) void k_stats_chan_d(const double* __restrict__ src,
                                                      double* __restrict__ partial) {
    int c = blockIdx.x;
    int chunk = blockIdx.y;
    const int SPLIT = 16;
    double s = 0.0, ss = 0.0;
    for (int j = chunk * 256 + threadIdx.x; j < R_; j += SPLIT * 256) {
        int b = j / N_, n = j - b * N_;
        double v = src[((size_t)b * C_ + c) * N_ + n];
        s += v;
        ss += v * v;
    }
    __shared__ double red[8];
    for (int off = 32; off; off >>= 1) {
        s += __shfl_down(s, off, 64);
        ss += __shfl_down(ss, off, 64);
    }
    int lane = threadIdx.x & 63, w = threadIdx.x >> 6;
    if (lane == 0) { red[w * 2] = s; red[w * 2 + 1] = ss; }
    __syncthreads();
    if (threadIdx.x == 0) {
        s = red[0] + red[2] + red[4] + red[6];
        ss = red[1] + red[3] + red[5] + red[7];
        partial[(c * SPLIT + chunk) * 2] = s;
        partial[(c * SPLIT + chunk) * 2 + 1] = ss;
    }
}

__global__ void k_stats_reduce_d(const double* __restrict__ partial, double* __restrict__ stats) {
    int c = blockIdx.x * blockDim.x + threadIdx.x;
    if (c >= 96) return;
    double s = 0.0, ss = 0.0;
    for (int k = 0; k < 16; k++) {
        s += partial[(c * 16 + k) * 2];
        ss += partial[(c * 16 + k) * 2 + 1];
    }
    double m = s / (double)R_;
    double var = ss / (double)R_ - m * m;
    stats[c * 2] = m;
    stats[c * 2 + 1] = 1.0 / sqrt(var + 1e-5);
}

// ---------------- fp32 stats reduce (interleaved partial layout) ----------------
__global__ void k_stats_reduce(const float* __restrict__ partial, float* __restrict__ stats,
                               int Cn, int SPLIT, float invcount) {
    int c = blockIdx.x * blockDim.x + threadIdx.x;
    if (c >= Cn) return;
    float s = 0.f, ss = 0.f;
    for (int k = 0; k < SPLIT; k++) {
        s += partial[(c * SPLIT + k) * 2];
        ss += partial[(c * SPLIT + k) * 2 + 1];
    }
    float m = s * invcount;
    float var = ss * invcount - m * m;
    stats[c * 2] = m;
    stats[c * 2 + 1] = 1.0f / sqrtf(var + EPS_);
}

// generalized block-partial reducer: partial[k*2*Cn + c] (sum), [k*2*Cn + Cn + c] (ss)
__global__ __launch_bounds__(256) void k_stats_reduce_g(const float* __restrict__ partial,
                                                        float* __restrict__ stats,
                                                        int Cn, int NB, float invcount) {
    int c = blockIdx.x;
    float s = 0.f, ss = 0.f;
    for (int k = threadIdx.x; k < NB; k += 256) {
        s  += partial[(size_t)k * 2 * Cn + c];
        ss += partial[(size_t)k * 2 * Cn + Cn + c];
    }
    __shared__ float red[8];
    for (int off = 32; off; off >>= 1) {
        s += __shfl_down(s, off, 64);
        ss += __shfl_down(ss, off, 64);
    }
    int lane = threadIdx.x & 63, w = threadIdx.x >> 6;
    if (lane == 0) { red[w * 2] = s; red[w * 2 + 1] = ss; }
    __syncthreads();
    if (threadIdx.x == 0) {
        s = red[0] + red[2] + red[4] + red[6];
        ss = red[1] + red[3] + red[5] + red[7];
        float m = s * invcount;
        float var = ss * invcount - m * m;
        stats[c * 2] = m;
        stats[c * 2 + 1] = 1.0f / sqrtf(var + EPS_);
    }
}

// ---------------- BN1 apply + LDS transpose ----------------
__global__ __launch_bounds__(256) void k_bn1_tr(const double* __restrict__ yd,
                                                const double* __restrict__ stats,
                                                const float* __restrict__ g,
                                                const float* __restrict__ be,
                                                float* __restrict__ ftc,
                                                double* __restrict__ ftp64,
                                                unsigned short* __restrict__ fspH,
                                                double* __restrict__ sq64) {
    __shared__ double tile[64 * 97];
    __shared__ double dsq[64][4];
    int b = blockIdx.y;
    int n0 = blockIdx.x * 64;
    int tid = threadIdx.x;
    int n = tid & 63, w = tid >> 6;
    for (int k = 0; k < 24; ++k) {
        int c = k * 4 + w;
        size_t gi = ((size_t)b * C_ + c) * N_ + n0 + n;
        double m = stats[c * 2], rs = stats[c * 2 + 1];
        double v = (double)g[c] * (yd[gi] - m) * rs + (double)be[c];
        ftc[gi] = (float)v;
        tile[n * 97 + c] = v;
    }
    __syncthreads();
    int p = n, q = w;
    double vals[24];
    double s = 0.0;
    const double* lp = &tile[p * 97 + q * 24];
#pragma unroll
    for (int m2 = 0; m2 < 24; ++m2) { vals[m2] = lp[m2]; s += vals[m2] * vals[m2]; }
    dsq[p][q] = s;
    double* dst = ftp64 + ((size_t)b * N_ + n0 + p) * C_ + q * 24;
#pragma unroll
    for (int m2 = 0; m2 < 24; m2 += 2) *(double2*)&dst[m2] = make_double2(vals[m2], vals[m2 + 1]);
    unsigned* hdst = (unsigned*)(fspH + ((size_t)b * N_ + n0 + p) * QS2);
#pragma unroll
    for (int m2 = 0; m2 < 24; m2 += 2) {
        unsigned u0 = __float_as_uint((float)vals[m2]);
        unsigned u1 = __float_as_uint((float)vals[m2 + 1]);
        unsigned h0 = (u0 + 0x7fffu + ((u0 >> 16) & 1u)) >> 16;      // RNE to bf16
        unsigned h1 = (u1 + 0x7fffu + ((u1 >> 16) & 1u)) >> 16;
        hdst[q * 12 + (m2 >> 1)] = h0 | (h1 << 16);
    }
    __syncthreads();
    if (tid < 64) {
        double tot = dsq[tid][0] + dsq[tid][1] + dsq[tid][2] + dsq[tid][3];
        sq64[(size_t)b * N_ + n0 + tid] = tot;
        float t32 = (float)(-0.5 * tot);
        unsigned u0 = __float_as_uint(t32);
        unsigned h0 = (u0 + 0x7fffu + ((u0 >> 16) & 1u)) >> 16;
        float resid = t32 - __uint_as_float(h0 << 16);
        unsigned u1 = __float_as_uint(resid);
        unsigned h1 = (u1 + 0x7fffu + ((u1 >> 16) & 1u)) >> 16;
        unsigned* hd = (unsigned*)(fspH + ((size_t)b * N_ + n0 + tid) * QS2);
        hd[48] = h0 | (h1 << 16);
#pragma unroll
        for (int k2 = 49; k2 < 64; ++k2) hd[k2] = 0u;
    }
}

// ---------------- single-kernel two-pass dist (r9 structure + norm folded as K-slice 3) ----------------
// block = 64 queries x all 3136 candidates (49 chunks of 64); 4 waves; XOR-swizzled LDS tiles;
// double-buffered chunk staging. pass 0: f32 per-query chunk minima -> exact t9; pass 1:
// compact d <= t9 + margin into LDS pool. d = -2*acc (candidate norm folded into MFMA).
__global__ __launch_bounds__(256) void k_dist6(const unsigned short* __restrict__ fspH,
                                               unsigned short* __restrict__ poolC,
                                               unsigned* __restrict__ poolCnt) {
    __shared__ __align__(16) char lds[54016];
    // buf0 [0,16384) | buf1 [16384,32768) | cminF [32768,45312) 49x64 f32 |
    // poolL [45312,53504) 64x64 u16 | cntL [53504,53760) | t9fL [53760,54016)
    float*          cminF = (float*)(lds + 32768);
    unsigned short* poolL = (unsigned short*)(lds + 45312);
    unsigned*       cntL  = (unsigned*)(lds + 53504);
    float*          t9fL  = (float*)(lds + 53760);

    int b = blockIdx.y;
    int q0 = blockIdx.x * 64;
    int tid = threadIdx.x;
    int w = tid >> 6, l = tid & 63;

    // stage queries into buf0 (swizzled), load query B-frags (+norm-select slice) to registers
    {
        const uint4* src = (const uint4*)(fspH + ((size_t)b * N_ + q0) * QS2);
        uint4* dst = (uint4*)lds;
        for (int i = tid; i < 1024; i += 256) dst[swz16(i)] = src[i];
    }
    __syncthreads();
    bf16x8 Bq[4];
    {
        const unsigned short* Ql = (const unsigned short*)lds;
        int qr = w * 16 + (l & 15);
#pragma unroll
        for (int s = 0; s < 3; ++s) {
            int col = (s * 4 + (l >> 4)) ^ (qr & 7);
            Bq[s] = *(const bf16x8*)&Ql[qr * QS2 + col * 8];
        }
        bf16x8 z = {0, 0, 0, 0, 0, 0, 0, 0};
        if ((l >> 4) == 0) { z[0] = (short)0x3F80; z[1] = (short)0x3F80; }   // bf16 1.0 at ch96/97
        Bq[3] = z;
    }
    __syncthreads();   // buf0 free

    // prologue: stage chunk 0 into buf0
    {
        const uint4* src = (const uint4*)(fspH + (size_t)b * N_ * QS2);
        uint4* dst = (uint4*)lds;
        for (int i = tid; i < 1024; i += 256) dst[swz16(i)] = src[i];
    }
    __syncthreads();

    float thr2r = 1e30f;     // acc-space threshold (keep if acc >= thr2r), set after pass 0
    int cur = 0;
    for (int t = 0; t < 98; ++t) {
        int ch = (t < 49) ? t : t - 49;
        int c0 = ch * 64;
        bool pf = (t < 97);
        uint4 st0, st1, st2, st3;
        if (pf) {
            int nch = (t + 1 < 49) ? (t + 1) : (t + 1 - 49);
            const uint4* src = (const uint4*)(fspH + ((size_t)b * N_ + nch * 64) * QS2);
            st0 = src[tid]; st1 = src[tid + 256]; st2 = src[tid + 512]; st3 = src[tid + 768];
        }
        const unsigned short* Bc = (const unsigned short*)(lds + cur * 16384);
        f32x4 acc[4];
#pragma unroll
        for (int ct = 0; ct < 4; ++ct) acc[ct] = (f32x4){0.f, 0.f, 0.f, 0.f};
#pragma unroll
        for (int s = 0; s < 4; ++s) {
#pragma unroll
            for (int ct = 0; ct < 4; ++ct) {
                int cr = ct * 16 + (l & 15);
                int col = (s * 4 + (l >> 4)) ^ (cr & 7);
                bf16x8 Ac = *(const bf16x8*)&Bc[cr * QS2 + col * 8];
                acc[ct] = __builtin_amdgcn_mfma_f32_16x16x32_bf16(Ac, Bq[s], acc[ct], 0, 0, 0);
            }
        }
        if (t < 49) {
            // per-query chunk-min of d = -2*acc  <=>  max over acc
            float mx = -1e30f;
#pragma unroll
            for (int ct = 0; ct < 4; ++ct)
#pragma unroll
                for (int j = 0; j < 4; ++j) mx = fmaxf(mx, acc[ct][j]);
            mx = fmaxf(mx, __shfl_xor(mx, 16, 64));
            mx = fmaxf(mx, __shfl_xor(mx, 32, 64));
            if (l < 16) cminF[ch * 64 + w * 16 + l] = -2.f * mx;
        } else {
            int qrow = w * 16 + (l & 15);
#pragma unroll
            for (int ct = 0; ct < 4; ++ct)
#pragma unroll
                for (int j = 0; j < 4; ++j) {
                    if (acc[ct][j] >= thr2r) {                       // rare
                        unsigned pos = atomicAdd(&cntL[qrow], 1u);
                        if (pos < (unsigned)CAP3)
                            poolL[qrow * CAP3 + pos] = (unsigned short)(c0 + ct * 16 + (l >> 4) * 4 + j);
                    }
                }
        }
        if (t == 48) {
            __syncthreads();     // all cmin written
            if (tid < 64) {
                float top[9];
#pragma unroll
                for (int j = 0; j < 9; ++j) top[j] = 1e30f;
                for (int q = 0; q < 49; ++q) {
                    float v = cminF[q * 64 + tid];
                    if (v < top[8]) {
                        top[8] = v;
#pragma unroll
                        for (int j = 8; j >= 1; --j)
                            if (top[j] < top[j - 1]) { float tt = top[j]; top[j] = top[j - 1]; top[j - 1] = tt; }
                    }
                }
                float t9 = top[8] + fabsf(top[8]) * 0.008f + 0.75f;  // hi-bf16 error margin
                t9fL[tid] = -0.5f * t9;                              // acc-space
                cntL[tid] = 0u;
            }
            __syncthreads();
            thr2r = t9fL[w * 16 + (l & 15)];
        }
        if (pf) {
            uint4* dst = (uint4*)(lds + (cur ^ 1) * 16384);
            dst[swz16(tid)] = st0;
            dst[swz16(tid + 256)] = st1;
            dst[swz16(tid + 512)] = st2;
            dst[swz16(tid + 768)] = st3;
        }
        __syncthreads();
        cur ^= 1;
    }
    if (tid < 64) {
        unsigned c = cntL[tid];
        poolCnt[(size_t)b * N_ + q0 + tid] = (c > (unsigned)CAP3) ? (unsigned)CAP3 : c;
    }
    {
        unsigned* dst = (unsigned*)(poolC + ((size_t)b * N_ + q0) * CAP3);
        const unsigned* src = (const unsigned*)poolL;
        for (int i = tid; i < 64 * CAP3 / 2; i += 256) dst[i] = src[i];
    }
}

// ---------------- fp64 exact re-rank of variable pool -> top-9 set ----------------
__global__ __launch_bounds__(256) void k_rerank_d(const unsigned short* __restrict__ poolC,
                                                  const unsigned* __restrict__ poolCnt,
                                                  const double* __restrict__ ftp64,
                                                  const double* __restrict__ sq64,
                                                  int* __restrict__ idx) {
    int tid = threadIdx.x;
    int wv = tid >> 6, l = tid & 63;
    int rr = blockIdx.x * 4 + wv;
    int b = rr / N_;
    int cnt = (int)poolCnt[rr];
    if (cnt > CAP3) cnt = CAP3;
    int e = l & 3;
    double qreg[24];
    {
        const double* qb = ftp64 + (size_t)rr * C_ + e * 24;
#pragma unroll
        for (int m = 0; m < 24; ++m) qreg[m] = qb[m];
    }
    double dv[4];
    int jv[4];
#pragma unroll
    for (int gG = 0; gG < 4; ++gG) { dv[gG] = 1e300; jv[gG] = 0x7fffffff; }
#pragma unroll
    for (int gG = 0; gG < 4; ++gG) {
        if (gG * 16 >= cnt) break;                 // wave-uniform skip
        int ci = gG * 16 + (l >> 2);
        bool valid = ci < cnt;
        int j = valid ? (int)poolC[(size_t)rr * CAP3 + ci] : 0;
        const double* cb = ftp64 + ((size_t)b * N_ + j) * C_ + e * 24;
        double p = 0.0;
#pragma unroll
        for (int m = 0; m < 24; ++m) p += qreg[m] * cb[m];
        p += __shfl_xor(p, 1, 64);
        p += __shfl_xor(p, 2, 64);
        if (valid) {
            dv[gG] = sq64[(size_t)b * N_ + j] - 2.0 * p;
            jv[gG] = j;
        }
    }
#pragma unroll
    for (int r = 0; r < 9; ++r) {
        double dm = dv[0]; int jm = jv[0];
#pragma unroll
        for (int gG = 1; gG < 4; ++gG)
            if (dv[gG] < dm || (dv[gG] == dm && jv[gG] < jm)) { dm = dv[gG]; jm = jv[gG]; }
#pragma unroll
        for (int off = 1; off <= 32; off <<= 1) {
            double od = __shfl_xor(dm, off, 64);
            int oj = __shfl_xor(jm, off, 64);
            if (od < dm || (od == dm && oj < jm)) { dm = od; jm = oj; }
        }
        if (l == 0) idx[(size_t)rr * 9 + r] = jm;
#pragma unroll
        for (int gG = 0; gG < 4; ++gG)
            if (jv[gG] == jm) dv[gG] = 1e300;
    }
}

// ---------------- fused: u = ft·(Wtop-Wbot)+b_edge AND v = ft·Wbot ----------------
__global__ __launch_bounds__(512) void k_gemm_uv2(const float* __restrict__ ftc,
                                                  const float* __restrict__ We,
                                                  const float* __restrict__ beb,
                                                  float* __restrict__ u,
                                                  float* __restrict__ v) {
    __shared__ float Wl[2][96 * 48];
    int tid = threadIdx.x;
    int rl = tid & 255, h = tid >> 8;
    int dbase = blockIdx.y * 48;
    for (int q = tid; q < 96 * 48; q += 512) {
        int c = q / 48, dd = q % 48;
        float wb = We[(96 + c) * C2_ + dbase + dd];
        Wl[1][q] = wb;
        Wl[0][q] = We[c * C2_ + dbase + dd] - wb;
    }
    __syncthreads();
    int r = blockIdx.x * 256 + rl;
    int b = r / N_, n = r - b * N_;
    float a0[24], a1[24];
#pragma unroll
    for (int i = 0; i < 24; i++) { a0[i] = 0.f; a1[i] = 0.f; }
    const float* xp = ftc + (size_t)b * C_ * N_ + n;
    for (int c = 0; c < 96; ++c) {
        float xv = xp[(size_t)c * N_];
        const float4* w40 = (const float4*)&Wl[0][c * 48 + h * 24];
        const float4* w41 = (const float4*)&Wl[1][c * 48 + h * 24];
#pragma unroll
        for (int i = 0; i < 6; ++i) {
            float4 w0 = w40[i], w1 = w41[i];
            a0[i * 4 + 0] += xv * w0.x; a0[i * 4 + 1] += xv * w0.y;
            a0[i * 4 + 2] += xv * w0.z; a0[i * 4 + 3] += xv * w0.w;
            a1[i * 4 + 0] += xv * w1.x; a1[i * 4 + 1] += xv * w1.y;
            a1[i * 4 + 2] += xv * w1.z; a1[i * 4 + 3] += xv * w1.w;
        }
    }
    int d0 = dbase + h * 24;
    float* up = u + (size_t)r * C2_ + d0;
    float* vp = v + (size_t)r * C2_ + d0;
#pragma unroll
    for (int i = 0; i < 6; ++i) {
        float4 ou, ov;
        ou.x = a0[i * 4 + 0] + beb[d0 + i * 4 + 0];
        ou.y = a0[i * 4 + 1] + beb[d0 + i * 4 + 1];
        ou.z = a0[i * 4 + 2] + beb[d0 + i * 4 + 2];
        ou.w = a0[i * 4 + 3] + beb[d0 + i * 4 + 3];
        ov.x = a1[i * 4 + 0]; ov.y = a1[i * 4 + 1];
        ov.z = a1[i * 4 + 2]; ov.w = a1[i * 4 + 3];
        ((float4*)up)[i] = ou;
        ((float4*)vp)[i] = ov;
    }
}

// ---------------- edge-BN stats: e = u[n,d] + v[j,d] over all (row,k) ----------------
__global__ __launch_bounds__(192) void k_bne_stats(const float* __restrict__ u,
                                                   const float* __restrict__ v,
                                                   const int* __restrict__ idx,
                                                   float* __restrict__ partial) {
    int d = threadIdx.x;
    int row0 = blockIdx.x * 32;
    int b = row0 / N_;
    float s = 0.f, ss = 0.f;
    for (int r = 0; r < 32; ++r) {
        int row = row0 + r;
        float ud = u[(size_t)row * C2_ + d];
        const int* ip = idx + (size_t)row * 9;
#pragma unroll
        for (int k = 0; k < 9; k++) {
            int j = ip[k];
            float e = ud + v[((size_t)b * N_ + j) * C2_ + d];
            s += e;
            ss += e * e;
        }
    }
    partial[(size_t)blockIdx.x * 384 + d] = s;
    partial[(size_t)blockIdx.x * 384 + 192 + d] = ss;
}

// ---------------- edge BN+relu+max over k, fc2 (192->96), fused out2 stats ----------------
__global__ __launch_bounds__(192) void k_edge_fc2_st(const float* __restrict__ u,
                                                     const float* __restrict__ v,
                                                     const int* __restrict__ idx,
                                                     const float* __restrict__ statsE,
                                                     const float* __restrict__ ge,
                                                     const float* __restrict__ bee,
                                                     const float* __restrict__ W2,
                                                     const float* __restrict__ b2,
                                                     float* __restrict__ out2,
                                                     float* __restrict__ partialE) {
    __shared__ float gl[16][C2_];
    __shared__ float g2[C_][16];
    int tid = threadIdx.x;
    int row0 = blockIdx.x * 16;
    int b = row0 / N_;
    int n0 = row0 - b * N_;
    {
        int d = tid;
        float m = statsE[d * 2], rs = statsE[d * 2 + 1];
        float ga = ge[d], bb = bee[d];
        for (int r = 0; r < 16; ++r) {
            int row = row0 + r;
            float ud = u[(size_t)row * C2_ + d];
            const int* ip = idx + (size_t)row * 9;
            float gm = 0.f;
#pragma unroll
            for (int k = 0; k < 9; k++) {
                int j = ip[k];
                float e = ud + v[((size_t)b * N_ + j) * C2_ + d];
                float val = ga * (e - m) * rs + bb;
                gm = fmaxf(gm, val);
            }
            gl[r][d] = gm;
        }
    }
    __syncthreads();
    {
        int rr = tid / 24;
        int dq = tid % 24;
        for (int rep = 0; rep < 2; ++rep) {
            int r = rr + rep * 8;
            float4 acc = *(const float4*)&b2[dq * 4];
            for (int d = 0; d < C2_; ++d) {
                float gv = gl[r][d];
                float4 w = *(const float4*)&W2[d * C_ + dq * 4];
                acc.x += gv * w.x;
                acc.y += gv * w.y;
                acc.z += gv * w.z;
                acc.w += gv * w.w;
            }
            g2[dq * 4 + 0][r] = acc.x;
            g2[dq * 4 + 1][r] = acc.y;
            g2[dq * 4 + 2][r] = acc.z;
            g2[dq * 4 + 3][r] = acc.w;
        }
    }
    __syncthreads();
    for (int q = tid; q < 96 * 4; q += 192) {
        int dd = q / 4, part = q % 4;
        float4 val = *(const float4*)&g2[dd][part * 4];
        *(float4*)&out2[((size_t)b * C_ + dd) * N_ + n0 + part * 4] = val;
    }
    {
        int c = tid >> 1, h = tid & 1;
        float s = 0.f, ss = 0.f;
#pragma unroll
        for (int r = 0; r < 8; ++r) {
            float vv = g2[c][h * 8 + r];
            s += vv;
            ss += vv * vv;
        }
        s += __shfl_xor(s, 1, 64);
        ss += __shfl_xor(ss, 1, 64);
        if (h == 0) {
            partialE[(size_t)blockIdx.x * 192 + c] = s;
            partialE[(size_t)blockIdx.x * 192 + 96 + c] = ss;
        }
    }
}

// ---------------- t = bn2(out2) + x, with fused per-channel stats of t ----------------
__global__ __launch_bounds__(256) void k_bn2_add_st(const float* __restrict__ out2,
                                                    const float* __restrict__ x,
                                                    const float* __restrict__ stats,
                                                    const float* __restrict__ g,
                                                    const float* __restrict__ be,
                                                    float* __restrict__ t,
                                                    float* __restrict__ partial) {
    int c = blockIdx.x;
    int chunk = blockIdx.y;
    const int SPLIT = 16;
    float m = stats[c * 2], rs = stats[c * 2 + 1];
    float ga = g[c], bb = be[c];
    float s = 0.f, ss = 0.f;
    for (int j = chunk * 256 + threadIdx.x; j < R_; j += SPLIT * 256) {
        int b = j / N_, n = j - b * N_;
        size_t i = ((size_t)b * C_ + c) * N_ + n;
        float tv = ga * (out2[i] - m) * rs + bb + x[i];
        t[i] = tv;
        s += tv;
        ss += tv * tv;
    }
    __shared__ float red[8];
    for (int off = 32; off; off >>= 1) {
        s += __shfl_down(s, off, 64);
        ss += __shfl_down(ss, off, 64);
    }
    int lane = threadIdx.x & 63, w = threadIdx.x >> 6;
    if (lane == 0) { red[w * 2] = s; red[w * 2 + 1] = ss; }
    __syncthreads();
    if (threadIdx.x == 0) {
        s = red[0] + red[2] + red[4] + red[6];
        ss = red[1] + red[3] + red[5] + red[7];
        partial[(c * SPLIT + chunk) * 2] = s;
        partial[(c * SPLIT + chunk) * 2 + 1] = ss;
    }
}

// ---------------- weight transpose for conv: Wt[(ic*9+q)*192 + oc] = Wd[oc*864 + ic*9 + q] ----------------
__global__ __launch_bounds__(256) void k_wtr(const float* __restrict__ Wd, float* __restrict__ Wt) {
    int i = blockIdx.x * 256 + threadIdx.x;
    if (i >= 192 * 864) return;
    int oc = i / 864, k = i % 864;
    Wt[(size_t)k * 192 + oc] = Wd[i];
}

// ---------------- conv 3x3 s2 p1, 96->192, 16 oc/block, scalar weight loads (no weight LDS),
// inline sabn+relu on input, fused z stats ----------------
__global__ __launch_bounds__(256) void k_conv16n(const float* __restrict__ t,
                                                 const float* __restrict__ statsS,
                                                 const float* __restrict__ gS,
                                                 const float* __restrict__ beS,
                                                 const float* __restrict__ Wt,
                                                 const float* __restrict__ bd,
                                                 float* __restrict__ z,
                                                 float* __restrict__ partialD) {
    __shared__ float redc[4][32];
    int b = blockIdx.z;
    int oc0 = blockIdx.y * 16;
    int p = blockIdx.x * 256 + threadIdx.x;
    bool valid = p < NO_;
    int oh = valid ? p / HO_ : 0, ow = valid ? p % HO_ : 0;
    float acc[16];
#pragma unroll
    for (int i = 0; i < 16; i++) acc[i] = 0.f;
    int ih0 = oh * 2 - 1, iw0 = ow * 2 - 1;
    const float* tb = t + (size_t)b * C_ * N_;
    for (int ic = 0; ic < 96; ++ic) {
        // sabn params via uniform (scalar) loads
        float m = statsS[ic * 2], rs = statsS[ic * 2 + 1], ga = gS[ic];
        float sc_ = ga * rs;
        float sh_ = beS[ic] - ga * m * rs;
        const float* sp = tb + (size_t)ic * N_;
        float in[9];
#pragma unroll
        for (int kh = 0; kh < 3; kh++) {
            int ih = ih0 + kh;
            bool okh = valid && ((unsigned)ih < 56u);
#pragma unroll
            for (int kw = 0; kw < 3; kw++) {
                int iw = iw0 + kw;
                bool ok = okh && ((unsigned)iw < 56u);
                float raw = ok ? sp[ih * 56 + iw] : 0.f;
                in[kh * 3 + kw] = ok ? fmaxf(sc_ * raw + sh_, 0.f) : 0.f;
            }
        }
        const float* wk = Wt + (size_t)(ic * 9) * 192 + oc0;
#pragma unroll
        for (int q = 0; q < 9; q++) {
            float iv = in[q];
            const float4* w4 = (const float4*)&wk[q * 192];     // uniform address -> s_load
#pragma unroll
            for (int j = 0; j < 4; j++) {
                float4 w = w4[j];
                acc[j * 4 + 0] += iv * w.x;
                acc[j * 4 + 1] += iv * w.y;
                acc[j * 4 + 2] += iv * w.z;
                acc[j * 4 + 3] += iv * w.w;
            }
        }
    }
    float s8[16];
#pragma unroll
    for (int i = 0; i < 16; i++) {
        float ov = acc[i] + bd[oc0 + i];
        if (valid) z[((size_t)b * OUP_ + oc0 + i) * NO_ + p] = ov;
        s8[i] = valid ? ov : 0.f;
    }
    int w = threadIdx.x >> 6;
#pragma unroll
    for (int i = 0; i < 16; ++i) {
        float s = s8[i], ss = s8[i] * s8[i];
        for (int off = 32; off; off >>= 1) {
            s += __shfl_down(s, off, 64);
            ss += __shfl_down(ss, off, 64);
        }
        if ((threadIdx.x & 63) == 0) { redc[w][i * 2] = s; redc[w][i * 2 + 1] = ss; }
    }
    __syncthreads();
    if (threadIdx.x < 32) {
        float v = redc[0][threadIdx.x] + redc[1][threadIdx.x] + redc[2][threadIdx.x] + redc[3][threadIdx.x];
        int blk = (b * 12 + blockIdx.y) * 4 + blockIdx.x;
        partialD[blk * 32 + threadIdx.x] = v;
    }
}

// reduce conv partials: 384 blocks x 16 oc each
__global__ void k_stats_reduce_conv(const float* __restrict__ partialD, float* __restrict__ stats) {
    int c = threadIdx.x;
    if (c >= 192) return;
    int y = c >> 4, o = c & 15;
    float s = 0.f, ss = 0.f;
    for (int bb = 0; bb < 8; ++bb)
        for (int x2 = 0; x2 < 4; ++x2) {
            int blk = (bb * 12 + y) * 4 + x2;
            s += partialD[blk * 32 + o * 2];
            ss += partialD[blk * 32 + o * 2 + 1];
        }
    float m = s / 6272.f;
    float var = ss / 6272.f - m * m;
    stats[c * 2] = m;
    stats[c * 2 + 1] = 1.0f / sqrtf(var + EPS_);
}

// ---------------- out = relu(dwbn(z)) ----------------
__global__ __launch_bounds__(256) void k_out(const float* __restrict__ z,
                                             const float* __restrict__ stats,
                                             const float* __restrict__ g,
                                             const float* __restrict__ be,
                                             float* __restrict__ out) {
    int i = blockIdx.x * 256 + threadIdx.x;
    if (i >= B_ * OUP_ * NO_) return;
    int c = (i / NO_) % OUP_;
    out[i] = fmaxf(g[c] * (z[i] - stats[c * 2]) * stats[c * 2 + 1] + be[c], 0.f);
}

extern "C" void kernel_launch(void* const* d_in, const int* in_sizes, int n_in,
                              void* d_out, int out_size, void* d_ws, size_t ws_size,
                              hipStream_t stream) {
    const float* x     = (const float*)d_in[0];
    const float* W_fc1 = (const float*)d_in[1];
    const float* b_fc1 = (const float*)d_in[2];
    const float* g_bn1 = (const float*)d_in[3];
    const float* be_bn1= (const float*)d_in[4];
    const float* W_edge= (const float*)d_in[5];
    const float* b_edge= (const float*)d_in[6];
    const float* g_bne = (const float*)d_in[7];
    const float* be_bne= (const float*)d_in[8];
    const float* W_fc2 = (const float*)d_in[9];
    const float* b_fc2 = (const float*)d_in[10];
    const float* g_bn2 = (const float*)d_in[11];
    const float* be_bn2= (const float*)d_in[12];
    const float* g_sabn= (const float*)d_in[13];
    const float* be_sabn=(const float*)d_in[14];
    const float* W_dw  = (const float*)d_in[15];
    const float* b_dw  = (const float*)d_in[16];
    const float* g_dwbn= (const float*)d_in[17];
    const float* be_dwbn=(const float*)d_in[18];

    // byte-offset workspace layout with lifetime-based aliasing (~75.5 MB)
    char* base = (char*)d_ws;
    float*  ftc   = (float*)(base + 0);                    //  9,633,792 [bn1_tr -> gemm]
    double* ftp64 = (double*)(base + 9633792);             // 19,267,584 [bn1_tr -> rerank]; then uu
    float*  uu    = (float*)(base + 9633792);
    double* yd    = (double*)(base + 28901376);            // 19,267,584 [fc1 -> bn1_tr]; then vv
    float*  vv    = (float*)(base + 28901376);
    unsigned short* fspH = (unsigned short*)(base + 48168960); // 6,422,528 [bn1_tr -> dist]; then out2
    float*  out2  = (float*)(base + 48168960);
    unsigned short* poolC = (unsigned short*)(base + 57802752); // 3,211,264 [dist -> rerank]; then tbuf
    float*  tbuf  = (float*)(base + 57802752);             //  9,633,792 [bn2 -> conv]
    double* sq64  = (double*)(base + 67436544);            //    200,704
    int*    idx   = (int*)(base + 67637248);               //    903,168 [rerank -> edge]
    unsigned* poolCnt = (unsigned*)(base + 68540416);      //    100,352
    float*  partial = (float*)(base + 68741120);           //  1,204,224 max (bne/partialE/bn2/partialD)
    double* partiald = (double*)(base + 68741120);         //     24,576 (earliest use, same region)
    double* stats1d = (double*)(base + 69945344);          //      1,536
    float*  statsE  = (float*)(base + 69946880);
    float*  stats2  = (float*)(base + 69948416);
    float*  statsS  = (float*)(base + 69949952);
    float*  statsD  = (float*)(base + 69951488);
    float*  zbuf  = (float*)(base + 69953024);             //  4,816,896 [conv -> out]
    float*  Wt    = (float*)(base + 74769920);             //    663,552 [wtr -> conv] -> ends 75,433,472

    // weight transpose (independent, launch first)
    k_wtr<<<648, 256, 0, stream>>>(W_dw, Wt);

    // fc1 + BN1 (fp64 path); bn1_tr fuses apply+transpose+bf16-split+norm-fold+sqrows
    k_fc1_d<<<dim3(98, 2), 512, 0, stream>>>(x, W_fc1, b_fc1, yd);
    k_stats_chan_d<<<dim3(96, 16), 256, 0, stream>>>(yd, partiald);
    k_stats_reduce_d<<<1, 256, 0, stream>>>(partiald, stats1d);
    k_bn1_tr<<<dim3(49, B_), 256, 0, stream>>>(yd, stats1d, g_bn1, be_bn1, ftc, ftp64, fspH, sq64);

    // kNN: single-kernel two-pass MFMA dist (norm-folded), then fp64 re-rank -> exact top-9
    k_dist6<<<dim3(49, B_), 256, 0, stream>>>(fspH, poolC, poolCnt);
    k_rerank_d<<<6272, 256, 0, stream>>>(poolC, poolCnt, ftp64, sq64, idx);

    // fused edge GEMMs: u = ft·(Wtop-Wbot)+b_edge, v = ft·Wbot (overwrite ftp64/yd)
    k_gemm_uv2<<<dim3(98, 4), 512, 0, stream>>>(ftc, W_edge, b_edge, uu, vv);

    // edge BN stats, then BN+relu+max+fc2 with fused out2 stats
    k_bne_stats<<<784, 192, 0, stream>>>(uu, vv, idx, partial);
    k_stats_reduce_g<<<192, 256, 0, stream>>>(partial, statsE, 192, 784, 1.0f / 225792.0f);
    k_edge_fc2_st<<<1568, 192, 0, stream>>>(uu, vv, idx, statsE, g_bne, be_bne, W_fc2, b_fc2, out2, partial);
    k_stats_reduce_g<<<96, 256, 0, stream>>>(partial, stats2, 96, 1568, 1.0f / (float)R_);

    // BN2 + shortcut (stats of t fused)
    k_bn2_add_st<<<dim3(96, 16), 256, 0, stream>>>(out2, x, stats2, g_bn2, be_bn2, tbuf, partial);
    k_stats_reduce<<<1, 256, 0, stream>>>(partial, statsS, 96, 16, 1.0f / (float)R_);

    // conv (inline sabn+relu, scalar weights, fused z stats) + dwbn + relu
    k_conv16n<<<dim3(4, 12, 8), 256, 0, stream>>>(tbuf, statsS, g_sabn, be_sabn, Wt, b_dw, zbuf, partial);
    k_stats_reduce_conv<<<1, 192, 0, stream>>>(partial, statsD);
    k_out<<<4705, 256, 0, stream>>>(zbuf, statsD, g_dwbn, be_dwbn, (float*)d_out);
}

// Round 13
// 587.729 us; speedup vs baseline: 1.1779x; 1.1671x over previous
//
#include <hip/hip_runtime.h>
#include <math.h>

#define B_   8
#define C_   96
#define C2_  192
#define N_   3136        // 56*56
#define R_   25088       // B_*N_
#define OUP_ 192
#define HO_  28
#define NO_  784         // 28*28
#define EPS_ 1e-5f
#define QS2  128         // fspH point stride in u16 (256 B); ch 96/97 = split(-sq/2), 98-127 zero
#define CAP3 64          // per-row candidate pool cap

typedef short bf16x8 __attribute__((ext_vector_type(8)));
typedef float f32x4  __attribute__((ext_vector_type(4)));

// uint4-slot XOR swizzle within a 64-row x 16-slot tile (T2): col ^= row&7
__device__ __forceinline__ int swz16(int i) { return (i & ~15) | ((i & 15) ^ ((i >> 4) & 7)); }

// ---------------- fc1 (fp64 accumulate): yd[b,d,n] = sum_c x[b,c,n]*W1[c,d] + b1[d] ----------------
__global__ __launch_bounds__(512) void k_fc1_d(const float* __restrict__ x,
                                               const float* __restrict__ W1,
                                               const float* __restrict__ b1,
                                               double* __restrict__ yd) {
    __shared__ double Wl[96 * 48];
    int tid = threadIdx.x;
    int rl = tid & 255, h = tid >> 8;
    int dbase = blockIdx.y * 48;
    for (int q = tid; q < 96 * 48; q += 512) {
        int c = q / 48, dd = q % 48;
        Wl[c * 48 + dd] = (double)W1[c * 96 + dbase + dd];
    }
    __syncthreads();
    int r = blockIdx.x * 256 + rl;
    int b = r / N_;
    int n = r - b * N_;
    double acc[24];
#pragma unroll
    for (int i = 0; i < 24; i++) acc[i] = 0.0;
    const float* xp = x + (size_t)b * C_ * N_ + n;
    for (int c = 0; c < 96; ++c) {
        double xv = (double)xp[(size_t)c * N_];
        const double* w = &Wl[c * 48 + h * 24];
#pragma unroll
        for (int i = 0; i < 24; ++i) acc[i] += xv * w[i];
    }
    int d0 = dbase + h * 24;
#pragma unroll
    for (int i = 0; i < 24; i++) {
        int d = d0 + i;
        yd[((size_t)b * C_ + d) * N_ + n] = acc[i] + (double)b1[d];
    }
}

// ---------------- fp64 per-channel stats over yd ----------------
__global__ __launch_bounds__(256) void k_stats_chan_d(const double* __restrict__ src,
                                                      double* __restrict__ partial) {
    int c = blockIdx.x;
    int chunk = blockIdx.y;
    const int SPLIT = 16;
    double s = 0.0, ss = 0.0;
    for (int j = chunk * 256 + threadIdx.x; j < R_; j += SPLIT * 256) {
        int b = j / N_, n = j - b * N_;
        double v = src[((size_t)b * C_ + c) * N_ + n];
        s += v;
        ss += v * v;
    }
    __shared__ double red[8];
    for (int off = 32; off; off >>= 1) {
        s += __shfl_down(s, off, 64);
        ss += __shfl_down(ss, off, 64);
    }
    int lane = threadIdx.x & 63, w = threadIdx.x >> 6;
    if (lane == 0) { red[w * 2] = s; red[w * 2 + 1] = ss; }
    __syncthreads();
    if (threadIdx.x == 0) {
        s = red[0] + red[2] + red[4] + red[6];
        ss = red[1] + red[3] + red[5] + red[7];
        partial[(c * SPLIT + chunk) * 2] = s;
        partial[(c * SPLIT + chunk) * 2 + 1] = ss;
    }
}

__global__ void k_stats_reduce_d(const double* __restrict__ partial, double* __restrict__ stats) {
    int c = blockIdx.x * blockDim.x + threadIdx.x;
    if (c >= 96) return;
    double s = 0.0, ss = 0.0;
    for (int k = 0; k < 16; k++) {
        s += partial[(c * 16 + k) * 2];
        ss += partial[(c * 16 + k) * 2 + 1];
    }
    double m = s / (double)R_;
    double var = ss / (double)R_ - m * m;
    stats[c * 2] = m;
    stats[c * 2 + 1] = 1.0 / sqrt(var + 1e-5);
}

// ---------------- fp32 stats reduce (interleaved partial layout) ----------------
__global__ void k_stats_reduce(const float* __restrict__ partial, float* __restrict__ stats,
                               int Cn, int SPLIT, float invcount) {
    int c = blockIdx.x * blockDim.x + threadIdx.x;
    if (c >= Cn) return;
    float s = 0.f, ss = 0.f;
    for (int k = 0; k < SPLIT; k++) {
        s += partial[(c * SPLIT + k) * 2];
        ss += partial[(c * SPLIT + k) * 2 + 1];
    }
    float m = s * invcount;
    float var = ss * invcount - m * m;
    stats[c * 2] = m;
    stats[c * 2 + 1] = 1.0f / sqrtf(var + EPS_);
}

// generalized block-partial reducer: partial[k*2*Cn + c] (sum), [k*2*Cn + Cn + c] (ss)
__global__ __launch_bounds__(256) void k_stats_reduce_g(const float* __restrict__ partial,
                                                        float* __restrict__ stats,
                                                        int Cn, int NB, float invcount) {
    int c = blockIdx.x;
    float s = 0.f, ss = 0.f;
    for (int k = threadIdx.x; k < NB; k += 256) {
        s  += partial[(size_t)k * 2 * Cn + c];
        ss += partial[(size_t)k * 2 * Cn + Cn + c];
    }
    __shared__ float red[8];
    for (int off = 32; off; off >>= 1) {
        s += __shfl_down(s, off, 64);
        ss += __shfl_down(ss, off, 64);
    }
    int lane = threadIdx.x & 63, w = threadIdx.x >> 6;
    if (lane == 0) { red[w * 2] = s; red[w * 2 + 1] = ss; }
    __syncthreads();
    if (threadIdx.x == 0) {
        s = red[0] + red[2] + red[4] + red[6];
        ss = red[1] + red[3] + red[5] + red[7];
        float m = s * invcount;
        float var = ss * invcount - m * m;
        stats[c * 2] = m;
        stats[c * 2 + 1] = 1.0f / sqrtf(var + EPS_);
    }
}

// ---------------- BN1 apply + LDS transpose ----------------
__global__ __launch_bounds__(256) void k_bn1_tr(const double* __restrict__ yd,
                                                const double* __restrict__ stats,
                                                const float* __restrict__ g,
                                                const float* __restrict__ be,
                                                float* __restrict__ ftc,
                                                double* __restrict__ ftp64,
                                                unsigned short* __restrict__ fspH,
                                                double* __restrict__ sq64) {
    __shared__ double tile[64 * 97];
    __shared__ double dsq[64][4];
    int b = blockIdx.y;
    int n0 = blockIdx.x * 64;
    int tid = threadIdx.x;
    int n = tid & 63, w = tid >> 6;
    for (int k = 0; k < 24; ++k) {
        int c = k * 4 + w;
        size_t gi = ((size_t)b * C_ + c) * N_ + n0 + n;
        double m = stats[c * 2], rs = stats[c * 2 + 1];
        double v = (double)g[c] * (yd[gi] - m) * rs + (double)be[c];
        ftc[gi] = (float)v;
        tile[n * 97 + c] = v;
    }
    __syncthreads();
    int p = n, q = w;
    double vals[24];
    double s = 0.0;
    const double* lp = &tile[p * 97 + q * 24];
#pragma unroll
    for (int m2 = 0; m2 < 24; ++m2) { vals[m2] = lp[m2]; s += vals[m2] * vals[m2]; }
    dsq[p][q] = s;
    double* dst = ftp64 + ((size_t)b * N_ + n0 + p) * C_ + q * 24;
#pragma unroll
    for (int m2 = 0; m2 < 24; m2 += 2) *(double2*)&dst[m2] = make_double2(vals[m2], vals[m2 + 1]);
    unsigned* hdst = (unsigned*)(fspH + ((size_t)b * N_ + n0 + p) * QS2);
#pragma unroll
    for (int m2 = 0; m2 < 24; m2 += 2) {
        unsigned u0 = __float_as_uint((float)vals[m2]);
        unsigned u1 = __float_as_uint((float)vals[m2 + 1]);
        unsigned h0 = (u0 + 0x7fffu + ((u0 >> 16) & 1u)) >> 16;      // RNE to bf16
        unsigned h1 = (u1 + 0x7fffu + ((u1 >> 16) & 1u)) >> 16;
        hdst[q * 12 + (m2 >> 1)] = h0 | (h1 << 16);
    }
    __syncthreads();
    if (tid < 64) {
        double tot = dsq[tid][0] + dsq[tid][1] + dsq[tid][2] + dsq[tid][3];
        sq64[(size_t)b * N_ + n0 + tid] = tot;
        float t32 = (float)(-0.5 * tot);
        unsigned u0 = __float_as_uint(t32);
        unsigned h0 = (u0 + 0x7fffu + ((u0 >> 16) & 1u)) >> 16;
        float resid = t32 - __uint_as_float(h0 << 16);
        unsigned u1 = __float_as_uint(resid);
        unsigned h1 = (u1 + 0x7fffu + ((u1 >> 16) & 1u)) >> 16;
        unsigned* hd = (unsigned*)(fspH + ((size_t)b * N_ + n0 + tid) * QS2);
        hd[48] = h0 | (h1 << 16);
#pragma unroll
        for (int k2 = 49; k2 < 64; ++k2) hd[k2] = 0u;
    }
}

// ---------------- single-kernel two-pass dist (norm folded as K-slice 3) ----------------
__global__ __launch_bounds__(256) void k_dist6(const unsigned short* __restrict__ fspH,
                                               unsigned short* __restrict__ poolC,
                                               unsigned* __restrict__ poolCnt) {
    __shared__ __align__(16) char lds[54016];
    // buf0 [0,16384) | buf1 [16384,32768) | cminF [32768,45312) 49x64 f32 |
    // poolL [45312,53504) 64x64 u16 | cntL [53504,53760) | t9fL [53760,54016)
    float*          cminF = (float*)(lds + 32768);
    unsigned short* poolL = (unsigned short*)(lds + 45312);
    unsigned*       cntL  = (unsigned*)(lds + 53504);
    float*          t9fL  = (float*)(lds + 53760);

    int b = blockIdx.y;
    int q0 = blockIdx.x * 64;
    int tid = threadIdx.x;
    int w = tid >> 6, l = tid & 63;

    // stage queries into buf0 (swizzled), load query B-frags (+norm-select slice) to registers
    {
        const uint4* src = (const uint4*)(fspH + ((size_t)b * N_ + q0) * QS2);
        uint4* dst = (uint4*)lds;
        for (int i = tid; i < 1024; i += 256) dst[swz16(i)] = src[i];
    }
    __syncthreads();
    bf16x8 Bq[4];
    {
        const unsigned short* Ql = (const unsigned short*)lds;
        int qr = w * 16 + (l & 15);
#pragma unroll
        for (int s = 0; s < 3; ++s) {
            int col = (s * 4 + (l >> 4)) ^ (qr & 7);
            Bq[s] = *(const bf16x8*)&Ql[qr * QS2 + col * 8];
        }
        bf16x8 z = {0, 0, 0, 0, 0, 0, 0, 0};
        if ((l >> 4) == 0) { z[0] = (short)0x3F80; z[1] = (short)0x3F80; }   // bf16 1.0 at ch96/97
        Bq[3] = z;
    }
    __syncthreads();   // buf0 free

    // prologue: stage chunk 0 into buf0
    {
        const uint4* src = (const uint4*)(fspH + (size_t)b * N_ * QS2);
        uint4* dst = (uint4*)lds;
        for (int i = tid; i < 1024; i += 256) dst[swz16(i)] = src[i];
    }
    __syncthreads();

    float thr2r = 1e30f;     // acc-space threshold (keep if acc >= thr2r), set after pass 0
    int cur = 0;
    for (int t = 0; t < 98; ++t) {
        int ch = (t < 49) ? t : t - 49;
        int c0 = ch * 64;
        bool pf = (t < 97);
        uint4 st0, st1, st2, st3;
        if (pf) {
            int nch = (t + 1 < 49) ? (t + 1) : (t + 1 - 49);
            const uint4* src = (const uint4*)(fspH + ((size_t)b * N_ + nch * 64) * QS2);
            st0 = src[tid]; st1 = src[tid + 256]; st2 = src[tid + 512]; st3 = src[tid + 768];
        }
        const unsigned short* Bc = (const unsigned short*)(lds + cur * 16384);
        f32x4 acc[4];
#pragma unroll
        for (int ct = 0; ct < 4; ++ct) acc[ct] = (f32x4){0.f, 0.f, 0.f, 0.f};
#pragma unroll
        for (int s = 0; s < 4; ++s) {
#pragma unroll
            for (int ct = 0; ct < 4; ++ct) {
                int cr = ct * 16 + (l & 15);
                int col = (s * 4 + (l >> 4)) ^ (cr & 7);
                bf16x8 Ac = *(const bf16x8*)&Bc[cr * QS2 + col * 8];
                acc[ct] = __builtin_amdgcn_mfma_f32_16x16x32_bf16(Ac, Bq[s], acc[ct], 0, 0, 0);
            }
        }
        if (t < 49) {
            float mx = -1e30f;
#pragma unroll
            for (int ct = 0; ct < 4; ++ct)
#pragma unroll
                for (int j = 0; j < 4; ++j) mx = fmaxf(mx, acc[ct][j]);
            mx = fmaxf(mx, __shfl_xor(mx, 16, 64));
            mx = fmaxf(mx, __shfl_xor(mx, 32, 64));
            if (l < 16) cminF[ch * 64 + w * 16 + l] = -2.f * mx;
        } else {
            int qrow = w * 16 + (l & 15);
#pragma unroll
            for (int ct = 0; ct < 4; ++ct)
#pragma unroll
                for (int j = 0; j < 4; ++j) {
                    if (acc[ct][j] >= thr2r) {                       // rare
                        unsigned pos = atomicAdd(&cntL[qrow], 1u);
                        if (pos < (unsigned)CAP3)
                            poolL[qrow * CAP3 + pos] = (unsigned short)(c0 + ct * 16 + (l >> 4) * 4 + j);
                    }
                }
        }
        if (t == 48) {
            __syncthreads();     // all cmin written
            if (tid < 64) {
                float top[9];
#pragma unroll
                for (int j = 0; j < 9; ++j) top[j] = 1e30f;
                for (int q = 0; q < 49; ++q) {
                    float v = cminF[q * 64 + tid];
                    if (v < top[8]) {
                        top[8] = v;
#pragma unroll
                        for (int j = 8; j >= 1; --j)
                            if (top[j] < top[j - 1]) { float tt = top[j]; top[j] = top[j - 1]; top[j - 1] = tt; }
                    }
                }
                float t9 = top[8] + fabsf(top[8]) * 0.008f + 0.75f;  // hi-bf16 error margin
                t9fL[tid] = -0.5f * t9;                              // acc-space
                cntL[tid] = 0u;
            }
            __syncthreads();
            thr2r = t9fL[w * 16 + (l & 15)];
        }
        if (pf) {
            uint4* dst = (uint4*)(lds + (cur ^ 1) * 16384);
            dst[swz16(tid)] = st0;
            dst[swz16(tid + 256)] = st1;
            dst[swz16(tid + 512)] = st2;
            dst[swz16(tid + 768)] = st3;
        }
        __syncthreads();
        cur ^= 1;
    }
    if (tid < 64) {
        unsigned c = cntL[tid];
        poolCnt[(size_t)b * N_ + q0 + tid] = (c > (unsigned)CAP3) ? (unsigned)CAP3 : c;
    }
    {
        unsigned* dst = (unsigned*)(poolC + ((size_t)b * N_ + q0) * CAP3);
        const unsigned* src = (const unsigned*)poolL;
        for (int i = tid; i < 64 * CAP3 / 2; i += 256) dst[i] = src[i];
    }
}

// ---------------- fp64 exact re-rank of variable pool -> top-9 set ----------------
__global__ __launch_bounds__(256) void k_rerank_d(const unsigned short* __restrict__ poolC,
                                                  const unsigned* __restrict__ poolCnt,
                                                  const double* __restrict__ ftp64,
                                                  const double* __restrict__ sq64,
                                                  int* __restrict__ idx) {
    int tid = threadIdx.x;
    int wv = tid >> 6, l = tid & 63;
    int rr = blockIdx.x * 4 + wv;
    int b = rr / N_;
    int cnt = (int)poolCnt[rr];
    if (cnt > CAP3) cnt = CAP3;
    int e = l & 3;
    double qreg[24];
    {
        const double* qb = ftp64 + (size_t)rr * C_ + e * 24;
#pragma unroll
        for (int m = 0; m < 24; ++m) qreg[m] = qb[m];
    }
    double dv[4];
    int jv[4];
#pragma unroll
    for (int gG = 0; gG < 4; ++gG) { dv[gG] = 1e300; jv[gG] = 0x7fffffff; }
#pragma unroll
    for (int gG = 0; gG < 4; ++gG) {
        if (gG * 16 >= cnt) break;                 // wave-uniform skip
        int ci = gG * 16 + (l >> 2);
        bool valid = ci < cnt;
        int j = valid ? (int)poolC[(size_t)rr * CAP3 + ci] : 0;
        const double* cb = ftp64 + ((size_t)b * N_ + j) * C_ + e * 24;
        double p = 0.0;
#pragma unroll
        for (int m = 0; m < 24; ++m) p += qreg[m] * cb[m];
        p += __shfl_xor(p, 1, 64);
        p += __shfl_xor(p, 2, 64);
        if (valid) {
            dv[gG] = sq64[(size_t)b * N_ + j] - 2.0 * p;
            jv[gG] = j;
        }
    }
#pragma unroll
    for (int r = 0; r < 9; ++r) {
        double dm = dv[0]; int jm = jv[0];
#pragma unroll
        for (int gG = 1; gG < 4; ++gG)
            if (dv[gG] < dm || (dv[gG] == dm && jv[gG] < jm)) { dm = dv[gG]; jm = jv[gG]; }
#pragma unroll
        for (int off = 1; off <= 32; off <<= 1) {
            double od = __shfl_xor(dm, off, 64);
            int oj = __shfl_xor(jm, off, 64);
            if (od < dm || (od == dm && oj < jm)) { dm = od; jm = oj; }
        }
        if (l == 0) idx[(size_t)rr * 9 + r] = jm;
#pragma unroll
        for (int gG = 0; gG < 4; ++gG)
            if (jv[gG] == jm) dv[gG] = 1e300;
    }
}

// ---------------- fused: u = ft·(Wtop-Wbot)+b_edge AND v = ft·Wbot ----------------
__global__ __launch_bounds__(512) void k_gemm_uv2(const float* __restrict__ ftc,
                                                  const float* __restrict__ We,
                                                  const float* __restrict__ beb,
                                                  float* __restrict__ u,
                                                  float* __restrict__ v) {
    __shared__ float Wl[2][96 * 48];
    int tid = threadIdx.x;
    int rl = tid & 255, h = tid >> 8;
    int dbase = blockIdx.y * 48;
    for (int q = tid; q < 96 * 48; q += 512) {
        int c = q / 48, dd = q % 48;
        float wb = We[(96 + c) * C2_ + dbase + dd];
        Wl[1][q] = wb;
        Wl[0][q] = We[c * C2_ + dbase + dd] - wb;
    }
    __syncthreads();
    int r = blockIdx.x * 256 + rl;
    int b = r / N_, n = r - b * N_;
    float a0[24], a1[24];
#pragma unroll
    for (int i = 0; i < 24; i++) { a0[i] = 0.f; a1[i] = 0.f; }
    const float* xp = ftc + (size_t)b * C_ * N_ + n;
    for (int c = 0; c < 96; ++c) {
        float xv = xp[(size_t)c * N_];
        const float4* w40 = (const float4*)&Wl[0][c * 48 + h * 24];
        const float4* w41 = (const float4*)&Wl[1][c * 48 + h * 24];
#pragma unroll
        for (int i = 0; i < 6; ++i) {
            float4 w0 = w40[i], w1 = w41[i];
            a0[i * 4 + 0] += xv * w0.x; a0[i * 4 + 1] += xv * w0.y;
            a0[i * 4 + 2] += xv * w0.z; a0[i * 4 + 3] += xv * w0.w;
            a1[i * 4 + 0] += xv * w1.x; a1[i * 4 + 1] += xv * w1.y;
            a1[i * 4 + 2] += xv * w1.z; a1[i * 4 + 3] += xv * w1.w;
        }
    }
    int d0 = dbase + h * 24;
    float* up = u + (size_t)r * C2_ + d0;
    float* vp = v + (size_t)r * C2_ + d0;
#pragma unroll
    for (int i = 0; i < 6; ++i) {
        float4 ou, ov;
        ou.x = a0[i * 4 + 0] + beb[d0 + i * 4 + 0];
        ou.y = a0[i * 4 + 1] + beb[d0 + i * 4 + 1];
        ou.z = a0[i * 4 + 2] + beb[d0 + i * 4 + 2];
        ou.w = a0[i * 4 + 3] + beb[d0 + i * 4 + 3];
        ov.x = a1[i * 4 + 0]; ov.y = a1[i * 4 + 1];
        ov.z = a1[i * 4 + 2]; ov.w = a1[i * 4 + 3];
        ((float4*)up)[i] = ou;
        ((float4*)vp)[i] = ov;
    }
}

// ---------------- edge-BN stats: e = u[n,d] + v[j,d] over all (row,k) ----------------
__global__ __launch_bounds__(192) void k_bne_stats(const float* __restrict__ u,
                                                   const float* __restrict__ v,
                                                   const int* __restrict__ idx,
                                                   float* __restrict__ partial) {
    int d = threadIdx.x;
    int row0 = blockIdx.x * 32;
    int b = row0 / N_;
    float s = 0.f, ss = 0.f;
    for (int r = 0; r < 32; ++r) {
        int row = row0 + r;
        float ud = u[(size_t)row * C2_ + d];
        const int* ip = idx + (size_t)row * 9;
#pragma unroll
        for (int k = 0; k < 9; k++) {
            int j = ip[k];
            float e = ud + v[((size_t)b * N_ + j) * C2_ + d];
            s += e;
            ss += e * e;
        }
    }
    partial[(size_t)blockIdx.x * 384 + d] = s;
    partial[(size_t)blockIdx.x * 384 + 192 + d] = ss;
}

// ---------------- edge BN+relu+max over k, fc2 (192->96), fused out2 stats ----------------
__global__ __launch_bounds__(192) void k_edge_fc2_st(const float* __restrict__ u,
                                                     const float* __restrict__ v,
                                                     const int* __restrict__ idx,
                                                     const float* __restrict__ statsE,
                                                     const float* __restrict__ ge,
                                                     const float* __restrict__ bee,
                                                     const float* __restrict__ W2,
                                                     const float* __restrict__ b2,
                                                     float* __restrict__ out2,
                                                     float* __restrict__ partialE) {
    __shared__ float gl[16][C2_];
    __shared__ float g2[C_][16];
    int tid = threadIdx.x;
    int row0 = blockIdx.x * 16;
    int b = row0 / N_;
    int n0 = row0 - b * N_;
    {
        int d = tid;
        float m = statsE[d * 2], rs = statsE[d * 2 + 1];
        float ga = ge[d], bb = bee[d];
        for (int r = 0; r < 16; ++r) {
            int row = row0 + r;
            float ud = u[(size_t)row * C2_ + d];
            const int* ip = idx + (size_t)row * 9;
            float gm = 0.f;
#pragma unroll
            for (int k = 0; k < 9; k++) {
                int j = ip[k];
                float e = ud + v[((size_t)b * N_ + j) * C2_ + d];
                float val = ga * (e - m) * rs + bb;
                gm = fmaxf(gm, val);
            }
            gl[r][d] = gm;
        }
    }
    __syncthreads();
    {
        int rr = tid / 24;
        int dq = tid % 24;
        for (int rep = 0; rep < 2; ++rep) {
            int r = rr + rep * 8;
            float4 acc = *(const float4*)&b2[dq * 4];
            for (int d = 0; d < C2_; ++d) {
                float gv = gl[r][d];
                float4 w = *(const float4*)&W2[d * C_ + dq * 4];
                acc.x += gv * w.x;
                acc.y += gv * w.y;
                acc.z += gv * w.z;
                acc.w += gv * w.w;
            }
            g2[dq * 4 + 0][r] = acc.x;
            g2[dq * 4 + 1][r] = acc.y;
            g2[dq * 4 + 2][r] = acc.z;
            g2[dq * 4 + 3][r] = acc.w;
        }
    }
    __syncthreads();
    for (int q = tid; q < 96 * 4; q += 192) {
        int dd = q / 4, part = q % 4;
        float4 val = *(const float4*)&g2[dd][part * 4];
        *(float4*)&out2[((size_t)b * C_ + dd) * N_ + n0 + part * 4] = val;
    }
    {
        int c = tid >> 1, h = tid & 1;
        float s = 0.f, ss = 0.f;
#pragma unroll
        for (int r = 0; r < 8; ++r) {
            float vv = g2[c][h * 8 + r];
            s += vv;
            ss += vv * vv;
        }
        s += __shfl_xor(s, 1, 64);
        ss += __shfl_xor(ss, 1, 64);
        if (h == 0) {
            partialE[(size_t)blockIdx.x * 192 + c] = s;
            partialE[(size_t)blockIdx.x * 192 + 96 + c] = ss;
        }
    }
}

// ---------------- t = bn2(out2) + x, with fused per-channel stats of t ----------------
__global__ __launch_bounds__(256) void k_bn2_add_st(const float* __restrict__ out2,
                                                    const float* __restrict__ x,
                                                    const float* __restrict__ stats,
                                                    const float* __restrict__ g,
                                                    const float* __restrict__ be,
                                                    float* __restrict__ t,
                                                    float* __restrict__ partial) {
    int c = blockIdx.x;
    int chunk = blockIdx.y;
    const int SPLIT = 16;
    float m = stats[c * 2], rs = stats[c * 2 + 1];
    float ga = g[c], bb = be[c];
    float s = 0.f, ss = 0.f;
    for (int j = chunk * 256 + threadIdx.x; j < R_; j += SPLIT * 256) {
        int b = j / N_, n = j - b * N_;
        size_t i = ((size_t)b * C_ + c) * N_ + n;
        float tv = ga * (out2[i] - m) * rs + bb + x[i];
        t[i] = tv;
        s += tv;
        ss += tv * tv;
    }
    __shared__ float red[8];
    for (int off = 32; off; off >>= 1) {
        s += __shfl_down(s, off, 64);
        ss += __shfl_down(ss, off, 64);
    }
    int lane = threadIdx.x & 63, w = threadIdx.x >> 6;
    if (lane == 0) { red[w * 2] = s; red[w * 2 + 1] = ss; }
    __syncthreads();
    if (threadIdx.x == 0) {
        s = red[0] + red[2] + red[4] + red[6];
        ss = red[1] + red[3] + red[5] + red[7];
        partial[(c * SPLIT + chunk) * 2] = s;
        partial[(c * SPLIT + chunk) * 2 + 1] = ss;
    }
}

// ---------------- conv 3x3 s2 p1, 96->192, ic-split halves (48 ic each), LDS weights,
// inline sabn+relu on input; writes zp[half] partials ----------------
__global__ __launch_bounds__(256) void k_conv_ic(const float* __restrict__ t,
                                                 const float* __restrict__ statsS,
                                                 const float* __restrict__ gS,
                                                 const float* __restrict__ beS,
                                                 const float* __restrict__ Wd,
                                                 float* __restrict__ zp) {
    __shared__ float Wl[48 * 9 * 16];   // 27648 B
    __shared__ float scl[48], shf[48];
    int b = blockIdx.z;
    int yy = blockIdx.y;
    int oc0 = (yy >> 1) * 16;
    int half = yy & 1;
    int icb = half * 48;
    int p = blockIdx.x * 256 + threadIdx.x;
    for (int i = threadIdx.x; i < 48 * 9 * 16; i += 256) {
        int oc = i & 15, icq = i >> 4;           // icq in [0,432)
        Wl[i] = Wd[(size_t)(oc0 + oc) * 864 + icb * 9 + icq];
    }
    if (threadIdx.x < 48) {
        int c = icb + threadIdx.x;
        float m = statsS[c * 2], rs = statsS[c * 2 + 1], ga = gS[c];
        scl[threadIdx.x] = ga * rs;
        shf[threadIdx.x] = beS[c] - ga * m * rs;
    }
    __syncthreads();
    if (p >= NO_) return;
    int oh = p / HO_, ow = p % HO_;
    float acc[16];
#pragma unroll
    for (int i = 0; i < 16; i++) acc[i] = 0.f;
    int ih0 = oh * 2 - 1, iw0 = ow * 2 - 1;
    const float* tb = t + (size_t)b * C_ * N_ + (size_t)icb * N_;
    for (int ic = 0; ic < 48; ++ic) {
        const float* sp = tb + (size_t)ic * N_;
        float sc_ = scl[ic], sh_ = shf[ic];
        float in[9];
#pragma unroll
        for (int kh = 0; kh < 3; kh++) {
            int ih = ih0 + kh;
            bool okh = (unsigned)ih < 56u;
#pragma unroll
            for (int kw = 0; kw < 3; kw++) {
                int iw = iw0 + kw;
                bool ok = okh && ((unsigned)iw < 56u);
                float raw = ok ? sp[ih * 56 + iw] : 0.f;
                in[kh * 3 + kw] = ok ? fmaxf(sc_ * raw + sh_, 0.f) : 0.f;
            }
        }
#pragma unroll
        for (int q = 0; q < 9; q++) {
            float iv = in[q];
            const float4* w4 = (const float4*)&Wl[(ic * 9 + q) * 16];
#pragma unroll
            for (int j = 0; j < 4; j++) {
                float4 w = w4[j];
                acc[j * 4 + 0] += iv * w.x;
                acc[j * 4 + 1] += iv * w.y;
                acc[j * 4 + 2] += iv * w.z;
                acc[j * 4 + 3] += iv * w.w;
            }
        }
    }
#pragma unroll
    for (int i = 0; i < 16; i++)
        zp[((size_t)(half * B_ + b) * OUP_ + oc0 + i) * NO_ + p] = acc[i];
}

// ---------------- z = zp0 + zp1 + bias, with fused per-channel stats ----------------
__global__ __launch_bounds__(256) void k_zcomb(const float* __restrict__ zp,
                                               const float* __restrict__ bd,
                                               float* __restrict__ z,
                                               float* __restrict__ partial) {
    int c = blockIdx.x;      // 0..191
    int chunk = blockIdx.y;  // 0..7
    const int SPLIT = 8;
    float bias = bd[c];
    float s = 0.f, ss = 0.f;
    for (int j = chunk * 256 + threadIdx.x; j < B_ * NO_; j += SPLIT * 256) {
        int b = j / NO_, p = j - b * NO_;
        size_t i = ((size_t)b * OUP_ + c) * NO_ + p;
        float v = zp[i] + zp[((size_t)(B_ + b) * OUP_ + c) * NO_ + p] + bias;
        z[i] = v;
        s += v;
        ss += v * v;
    }
    __shared__ float red[8];
    for (int off = 32; off; off >>= 1) {
        s += __shfl_down(s, off, 64);
        ss += __shfl_down(ss, off, 64);
    }
    int lane = threadIdx.x & 63, w = threadIdx.x >> 6;
    if (lane == 0) { red[w * 2] = s; red[w * 2 + 1] = ss; }
    __syncthreads();
    if (threadIdx.x == 0) {
        s = red[0] + red[2] + red[4] + red[6];
        ss = red[1] + red[3] + red[5] + red[7];
        partial[(c * SPLIT + chunk) * 2] = s;
        partial[(c * SPLIT + chunk) * 2 + 1] = ss;
    }
}

// ---------------- out = relu(dwbn(z)) ----------------
__global__ __launch_bounds__(256) void k_out(const float* __restrict__ z,
                                             const float* __restrict__ stats,
                                             const float* __restrict__ g,
                                             const float* __restrict__ be,
                                             float* __restrict__ out) {
    int i = blockIdx.x * 256 + threadIdx.x;
    if (i >= B_ * OUP_ * NO_) return;
    int c = (i / NO_) % OUP_;
    out[i] = fmaxf(g[c] * (z[i] - stats[c * 2]) * stats[c * 2 + 1] + be[c], 0.f);
}

extern "C" void kernel_launch(void* const* d_in, const int* in_sizes, int n_in,
                              void* d_out, int out_size, void* d_ws, size_t ws_size,
                              hipStream_t stream) {
    const float* x     = (const float*)d_in[0];
    const float* W_fc1 = (const float*)d_in[1];
    const float* b_fc1 = (const float*)d_in[2];
    const float* g_bn1 = (const float*)d_in[3];
    const float* be_bn1= (const float*)d_in[4];
    const float* W_edge= (const float*)d_in[5];
    const float* b_edge= (const float*)d_in[6];
    const float* g_bne = (const float*)d_in[7];
    const float* be_bne= (const float*)d_in[8];
    const float* W_fc2 = (const float*)d_in[9];
    const float* b_fc2 = (const float*)d_in[10];
    const float* g_bn2 = (const float*)d_in[11];
    const float* be_bn2= (const float*)d_in[12];
    const float* g_sabn= (const float*)d_in[13];
    const float* be_sabn=(const float*)d_in[14];
    const float* W_dw  = (const float*)d_in[15];
    const float* b_dw  = (const float*)d_in[16];
    const float* g_dwbn= (const float*)d_in[17];
    const float* be_dwbn=(const float*)d_in[18];

    // byte-offset workspace layout with lifetime-based aliasing (~74.8 MB)
    char* base = (char*)d_ws;
    float*  ftc   = (float*)(base + 0);                    //  9,633,792 [bn1_tr -> gemm]; then zp
    float*  zp    = (float*)(base + 0);                    //  9,633,792 [conv_ic -> zcomb]
    double* ftp64 = (double*)(base + 9633792);             // 19,267,584 [bn1_tr -> rerank]; then uu
    float*  uu    = (float*)(base + 9633792);
    double* yd    = (double*)(base + 28901376);            // 19,267,584 [fc1 -> bn1_tr]; then vv
    float*  vv    = (float*)(base + 28901376);
    unsigned short* fspH = (unsigned short*)(base + 48168960); // 6,422,528 [bn1_tr -> dist]; then out2
    float*  out2  = (float*)(base + 48168960);
    unsigned short* poolC = (unsigned short*)(base + 57802752); // 3,211,264 [dist -> rerank]; then tbuf
    float*  tbuf  = (float*)(base + 57802752);             //  9,633,792 [bn2 -> conv]
    double* sq64  = (double*)(base + 67436544);            //    200,704
    int*    idx   = (int*)(base + 67637248);               //    903,168 [rerank -> edge]
    unsigned* poolCnt = (unsigned*)(base + 68540416);      //    100,352
    float*  partial = (float*)(base + 68741120);           //  1,204,224 max (bne/partialE/bn2/zcomb)
    double* partiald = (double*)(base + 68741120);         //     24,576 (earliest use, same region)
    double* stats1d = (double*)(base + 69945344);          //      1,536
    float*  statsE  = (float*)(base + 69946880);
    float*  stats2  = (float*)(base + 69948416);
    float*  statsS  = (float*)(base + 69949952);
    float*  statsD  = (float*)(base + 69951488);
    float*  zbuf  = (float*)(base + 69953024);             //  4,816,896 [zcomb -> out] -> ends 74,769,920

    // fc1 + BN1 (fp64 path); bn1_tr fuses apply+transpose+bf16-split+norm-fold+sqrows
    k_fc1_d<<<dim3(98, 2), 512, 0, stream>>>(x, W_fc1, b_fc1, yd);
    k_stats_chan_d<<<dim3(96, 16), 256, 0, stream>>>(yd, partiald);
    k_stats_reduce_d<<<1, 256, 0, stream>>>(partiald, stats1d);
    k_bn1_tr<<<dim3(49, B_), 256, 0, stream>>>(yd, stats1d, g_bn1, be_bn1, ftc, ftp64, fspH, sq64);

    // kNN: single-kernel two-pass MFMA dist (norm-folded), then fp64 re-rank -> exact top-9
    k_dist6<<<dim3(49, B_), 256, 0, stream>>>(fspH, poolC, poolCnt);
    k_rerank_d<<<6272, 256, 0, stream>>>(poolC, poolCnt, ftp64, sq64, idx);

    // fused edge GEMMs: u = ft·(Wtop-Wbot)+b_edge, v = ft·Wbot (overwrite ftp64/yd)
    k_gemm_uv2<<<dim3(98, 4), 512, 0, stream>>>(ftc, W_edge, b_edge, uu, vv);

    // edge BN stats, then BN+relu+max+fc2 with fused out2 stats
    k_bne_stats<<<784, 192, 0, stream>>>(uu, vv, idx, partial);
    k_stats_reduce_g<<<192, 256, 0, stream>>>(partial, statsE, 192, 784, 1.0f / 225792.0f);
    k_edge_fc2_st<<<1568, 192, 0, stream>>>(uu, vv, idx, statsE, g_bne, be_bne, W_fc2, b_fc2, out2, partial);
    k_stats_reduce_g<<<96, 256, 0, stream>>>(partial, stats2, 96, 1568, 1.0f / (float)R_);

    // BN2 + shortcut (stats of t fused)
    k_bn2_add_st<<<dim3(96, 16), 256, 0, stream>>>(out2, x, stats2, g_bn2, be_bn2, tbuf, partial);
    k_stats_reduce<<<1, 256, 0, stream>>>(partial, statsS, 96, 16, 1.0f / (float)R_);

    // conv: ic-split halves (inline sabn+relu, LDS weights) -> zp; combine + fused z stats
    k_conv_ic<<<dim3(4, 24, 8), 256, 0, stream>>>(tbuf, statsS, g_sabn, be_sabn, W_dw, zp);
    k_zcomb<<<dim3(192, 8), 256, 0, stream>>>(zp, b_dw, zbuf, partial);
    k_stats_reduce<<<1, 256, 0, stream>>>(partial, statsD, 192, 8, 1.0f / 6272.0f);
    k_out<<<4705, 256, 0, stream>>>(zbuf, statsD, g_dwbn, be_dwbn, (float*)d_out);
}